// Round 1
// baseline (323.669 us; speedup 1.0000x reference)
//
#include <hip/hip_runtime.h>
#include <stdint.h>

#define S_LEN 2048
#define D_DIM 64
#define NBH   64      // B*H = 4*16
#define KVB   64      // kv tile rows
#define QB    64      // q rows per block (16 per wave)
#define DPAD  72      // 64 + 8 bf16 pad -> kills 128B-stride bank conflicts

typedef __bf16 bf8_t __attribute__((ext_vector_type(8)));
typedef short  sv8   __attribute__((ext_vector_type(8)));
typedef float  f32x4 __attribute__((ext_vector_type(4)));

static __device__ __forceinline__ unsigned short f2bf(float x) {
  union { float f; unsigned int u; } v; v.f = x;
  unsigned int r = v.u + 0x7FFFu + ((v.u >> 16) & 1u);  // RNE
  return (unsigned short)(r >> 16);
}
static __device__ __forceinline__ float bf2f(unsigned short h) {
  union { float f; unsigned int u; } v; v.u = ((unsigned int)h) << 16;
  return v.f;
}
static __device__ __forceinline__ f32x4 mfma_bf16(sv8 a, sv8 b, f32x4 c) {
  union { sv8 s; bf8_t b; } ua, ub; ua.s = a; ub.s = b;
  return __builtin_amdgcn_mfma_f32_16x16x32_bf16(ua.b, ub.b, c, 0, 0, 0);
}

extern "C" __global__ void __launch_bounds__(256)
attn_fwd(const float* __restrict__ Qg, const float* __restrict__ Kg,
         const float* __restrict__ Vg, float* __restrict__ Og) {
  __shared__ unsigned short Khi[KVB][DPAD];
  __shared__ unsigned short Klo[KVB][DPAD];
  __shared__ unsigned short Vt[D_DIM][DPAD];   // [d][kv]
  __shared__ unsigned short Pl[4][16][DPAD];   // per-wave P staging

  const int tid  = threadIdx.x;
  const int wave = tid >> 6;
  const int lane = tid & 63;
  const int bh   = blockIdx.y;
  const int q0   = blockIdx.x * QB;
  const int lg   = lane >> 4;   // 0..3
  const int lc   = lane & 15;
  const int kg   = lg << 3;     // 0,8,16,24

  const size_t headoff = (size_t)bh * S_LEN * D_DIM;
  const float scale = 0.28867513459481287f;   // 1/sqrt(12)

  // ---- Q fragments (hi/lo split), held in registers for the whole kernel
  sv8 qh[2], ql[2];
  {
    const float* qp = Qg + headoff + (size_t)(q0 + wave * 16 + lc) * D_DIM;
#pragma unroll
    for (int c = 0; c < 2; ++c) {
      const float4 a0 = *reinterpret_cast<const float4*>(qp + c * 32 + kg);
      const float4 a1 = *reinterpret_cast<const float4*>(qp + c * 32 + kg + 4);
      float qv[8] = {a0.x, a0.y, a0.z, a0.w, a1.x, a1.y, a1.z, a1.w};
#pragma unroll
      for (int j = 0; j < 8; ++j) {
        unsigned short h = f2bf(qv[j]);
        qh[c][j] = (short)h;
        ql[c][j] = (short)f2bf(qv[j] - bf2f(h));
      }
    }
  }

  float mrun[4], lrun[4];
  f32x4 oacc[4];
#pragma unroll
  for (int r = 0; r < 4; ++r) { mrun[r] = -__builtin_inff(); lrun[r] = 0.f; }
#pragma unroll
  for (int t = 0; t < 4; ++t) oacc[t] = (f32x4){0.f, 0.f, 0.f, 0.f};

  const int srow = tid >> 2;          // 0..63 staging row
  const int sd   = (tid & 3) << 4;    // 0,16,32,48
  const float* kbase = Kg + headoff + sd;
  const float* vbase = Vg + headoff + sd;

  for (int kv0 = 0; kv0 < S_LEN; kv0 += KVB) {
    // ---- stage K (hi/lo) and V^T into LDS, fp32 -> bf16
    {
      const float* kp = kbase + (size_t)(kv0 + srow) * D_DIM;
      const float* vp = vbase + (size_t)(kv0 + srow) * D_DIM;
#pragma unroll
      for (int i = 0; i < 16; i += 4) {
        float4 kf = *reinterpret_cast<const float4*>(kp + i);
        unsigned short h0 = f2bf(kf.x), h1 = f2bf(kf.y), h2 = f2bf(kf.z), h3 = f2bf(kf.w);
        *reinterpret_cast<uint64_t*>(&Khi[srow][sd + i]) =
            (uint64_t)h0 | ((uint64_t)h1 << 16) | ((uint64_t)h2 << 32) | ((uint64_t)h3 << 48);
        unsigned short l0 = f2bf(kf.x - bf2f(h0)), l1 = f2bf(kf.y - bf2f(h1));
        unsigned short l2 = f2bf(kf.z - bf2f(h2)), l3 = f2bf(kf.w - bf2f(h3));
        *reinterpret_cast<uint64_t*>(&Klo[srow][sd + i]) =
            (uint64_t)l0 | ((uint64_t)l1 << 16) | ((uint64_t)l2 << 32) | ((uint64_t)l3 << 48);
        float4 vf = *reinterpret_cast<const float4*>(vp + i);
        Vt[sd + i + 0][srow] = f2bf(vf.x);
        Vt[sd + i + 1][srow] = f2bf(vf.y);
        Vt[sd + i + 2][srow] = f2bf(vf.z);
        Vt[sd + i + 3][srow] = f2bf(vf.w);
      }
    }
    __syncthreads();

    // ---- S = Q K^T (hi/lo split: qh*kh + qh*kl + ql*kh)
    f32x4 sacc[4];
#pragma unroll
    for (int t = 0; t < 4; ++t) sacc[t] = (f32x4){0.f, 0.f, 0.f, 0.f};
#pragma unroll
    for (int t = 0; t < 4; ++t) {
#pragma unroll
      for (int c = 0; c < 2; ++c) {
        sv8 khv = *reinterpret_cast<const sv8*>(&Khi[t * 16 + lc][c * 32 + kg]);
        sv8 klv = *reinterpret_cast<const sv8*>(&Klo[t * 16 + lc][c * 32 + kg]);
        sacc[t] = mfma_bf16(qh[c], khv, sacc[t]);
        sacc[t] = mfma_bf16(qh[c], klv, sacc[t]);
        sacc[t] = mfma_bf16(ql[c], khv, sacc[t]);
      }
    }

    // ---- online softmax (rows live across lanes of the 16-lane group)
    float p[4][4], pm[4], rs[4];
#pragma unroll
    for (int r = 0; r < 4; ++r) {
      float a = fmaxf(fmaxf(sacc[0][r], sacc[1][r]), fmaxf(sacc[2][r], sacc[3][r]));
      pm[r] = a * scale;
    }
#pragma unroll
    for (int msk = 1; msk < 16; msk <<= 1)
#pragma unroll
      for (int r = 0; r < 4; ++r)
        pm[r] = fmaxf(pm[r], __shfl_xor(pm[r], msk));
#pragma unroll
    for (int r = 0; r < 4; ++r) {
      float mnew = fmaxf(mrun[r], pm[r]);
      float fsc  = __expf(mrun[r] - mnew);
      mrun[r] = mnew;
      float s0 = 0.f;
#pragma unroll
      for (int t = 0; t < 4; ++t) {
        float pv = __expf(sacc[t][r] * scale - mnew);
        p[t][r] = pv; s0 += pv;
      }
      rs[r] = s0;
      lrun[r] *= fsc;
#pragma unroll
      for (int t = 0; t < 4; ++t) oacc[t][r] *= fsc;
    }
#pragma unroll
    for (int msk = 1; msk < 16; msk <<= 1)
#pragma unroll
      for (int r = 0; r < 4; ++r)
        rs[r] += __shfl_xor(rs[r], msk);
#pragma unroll
    for (int r = 0; r < 4; ++r) lrun[r] += rs[r];

    // ---- P -> LDS (transpose C/D layout -> A-fragment layout)
#pragma unroll
    for (int r = 0; r < 4; ++r)
#pragma unroll
      for (int t = 0; t < 4; ++t)
        Pl[wave][lg * 4 + r][t * 16 + lc] = f2bf(p[t][r]);

    // ---- O += P V
#pragma unroll
    for (int dt = 0; dt < 4; ++dt) {
#pragma unroll
      for (int kc = 0; kc < 2; ++kc) {
        sv8 pa = *reinterpret_cast<const sv8*>(&Pl[wave][lc][kc * 32 + kg]);
        sv8 vb = *reinterpret_cast<const sv8*>(&Vt[dt * 16 + lc][kc * 32 + kg]);
        oacc[dt] = mfma_bf16(pa, vb, oacc[dt]);
      }
    }
    __syncthreads();
  }

  // ---- epilogue: normalize and store
  float* op = Og + headoff + (size_t)(q0 + wave * 16) * D_DIM;
#pragma unroll
  for (int r = 0; r < 4; ++r) {
    float inv = 1.0f / lrun[r];
    int row = lg * 4 + r;
#pragma unroll
    for (int dt = 0; dt < 4; ++dt)
      op[(size_t)row * D_DIM + dt * 16 + lc] = oacc[dt][r] * inv;
  }
}

extern "C" void kernel_launch(void* const* d_in, const int* in_sizes, int n_in,
                              void* d_out, int out_size, void* d_ws, size_t ws_size,
                              hipStream_t stream) {
  const float* Q = (const float*)d_in[0];
  const float* K = (const float*)d_in[1];
  const float* V = (const float*)d_in[2];
  float* O = (float*)d_out;
  dim3 grid(S_LEN / QB, NBH);
  attn_fwd<<<grid, dim3(256), 0, stream>>>(Q, K, V, O);
}

// Round 2
// 194.638 us; speedup vs baseline: 1.6629x; 1.6629x over previous
//
#include <hip/hip_runtime.h>
#include <stdint.h>

#define S_LEN 2048
#define D_DIM 64
#define NBH   64              // B*H
#define QB    64              // q rows per block (16 per wave)
#define NT    (S_LEN / 64)    // 32 kv tiles
#define TILE_SHORTS 8192      // 16KB per kv tile: K frags 8KB + V frags 8KB

typedef __bf16 bf8_t __attribute__((ext_vector_type(8)));
typedef short  sv8   __attribute__((ext_vector_type(8)));
typedef float  f32x4 __attribute__((ext_vector_type(4)));
typedef __attribute__((address_space(1))) uint32_t gu32;
typedef __attribute__((address_space(3))) uint32_t lu32;

static __device__ __forceinline__ unsigned short f2bf(float x) {
  union { float f; unsigned int u; } v; v.f = x;
  unsigned int r = v.u + 0x7FFFu + ((v.u >> 16) & 1u);  // RNE
  return (unsigned short)(r >> 16);
}
static __device__ __forceinline__ float bf2f(unsigned short h) {
  union { float f; unsigned int u; } v; v.u = ((unsigned int)h) << 16;
  return v.f;
}
static __device__ __forceinline__ f32x4 mfma_bf16(sv8 a, sv8 b, f32x4 c) {
  union { sv8 s; bf8_t b; } ua, ub; ua.s = a; ub.s = b;
  return __builtin_amdgcn_mfma_f32_16x16x32_bf16(ua.b, ub.b, c, 0, 0, 0);
}

// ---------------- pre-pass: K,V fp32 -> bf16 MFMA fragment order in d_ws ----
// ws layout per (bh,tile): 1024 slots x 16B.
//  slots   0..511 : K  A-frag. slot s: chunk=s>>6 (t=chunk>>1,c=chunk&1), lane=s&63
//                   elems j: K[kv0+16t+(lane&15)][32c+8*(lane>>4)+j]
//  slots 512..1023: V  B-frag. slot s: chunk (dt=chunk>>1,kc=chunk&1), lane
//                   elems j: V[kv0+32kc+8*(lane>>4)+j][16dt+(lane&15)]
extern "C" __global__ void __launch_bounds__(256)
prep_kv(const float* __restrict__ Kg, const float* __restrict__ Vg,
        unsigned short* __restrict__ Wf) {
  const int tile = blockIdx.x, bh = blockIdx.y, tid = threadIdx.x;
  const size_t in_head = (size_t)bh * S_LEN * D_DIM;
  unsigned short* out = Wf + (size_t)(bh * NT + tile) * TILE_SHORTS;

#pragma unroll
  for (int k8 = 0; k8 < 2; ++k8) {     // K slots
    int s = tid + 256 * k8;
    int chunk = s >> 6, lane = s & 63;
    int t = chunk >> 1, c = chunk & 1, lc = lane & 15, lg = lane >> 4;
    const float* p = Kg + in_head + (size_t)(tile * 64 + 16 * t + lc) * D_DIM + 32 * c + 8 * lg;
    float4 f0 = *(const float4*)p;
    float4 f1 = *(const float4*)(p + 4);
    uint4 w;
    w.x = (uint32_t)f2bf(f0.x) | ((uint32_t)f2bf(f0.y) << 16);
    w.y = (uint32_t)f2bf(f0.z) | ((uint32_t)f2bf(f0.w) << 16);
    w.z = (uint32_t)f2bf(f1.x) | ((uint32_t)f2bf(f1.y) << 16);
    w.w = (uint32_t)f2bf(f1.z) | ((uint32_t)f2bf(f1.w) << 16);
    *(uint4*)(out + (size_t)s * 8) = w;
  }
#pragma unroll
  for (int k8 = 0; k8 < 2; ++k8) {     // V slots (transpose)
    int s = tid + 256 * k8;
    int chunk = s >> 6, lane = s & 63;
    int dt = chunk >> 1, kc = chunk & 1, lc = lane & 15, lg = lane >> 4;
    const float* p = Vg + in_head + (size_t)(tile * 64 + 32 * kc + 8 * lg) * D_DIM + 16 * dt + lc;
    uint32_t hw[4];
#pragma unroll
    for (int jj = 0; jj < 4; ++jj) {
      unsigned short a = f2bf(p[(size_t)(2 * jj) * D_DIM]);
      unsigned short b = f2bf(p[(size_t)(2 * jj + 1) * D_DIM]);
      hw[jj] = (uint32_t)a | ((uint32_t)b << 16);
    }
    uint4 w = {hw[0], hw[1], hw[2], hw[3]};
    *(uint4*)(out + (size_t)(512 + s) * 8) = w;
  }
}

// ---------------- main attention kernel -------------------------------------
extern "C" __global__ void __launch_bounds__(256)
attn_fwd(const float* __restrict__ Qg, const unsigned short* __restrict__ Wf,
         float* __restrict__ Og) {
  __shared__ short KV[2][TILE_SHORTS];  // double-buffered tile (32KB)
  __shared__ short Pw[4][1024];         // per-wave P, chunk-XOR swizzled (8KB)

  const int tid = threadIdx.x, wave = tid >> 6, lane = tid & 63;
  const int lg = lane >> 4, lc = lane & 15;
  const int bh = blockIdx.y, q0 = blockIdx.x * QB;
  const size_t headoff = (size_t)bh * S_LEN * D_DIM;

  // Q B-fragments, pre-scaled by (1/sqrt(12))*log2(e), hi/lo split
  const float s2 = 0.28867513459481287f * 1.44269504088896340f;
  sv8 qh[2], ql[2];
  {
    const float* qp = Qg + headoff + (size_t)(q0 + wave * 16 + lc) * D_DIM;
#pragma unroll
    for (int c = 0; c < 2; ++c) {
      float4 a0 = *(const float4*)(qp + c * 32 + 8 * lg);
      float4 a1 = *(const float4*)(qp + c * 32 + 8 * lg + 4);
      float qv[8] = {a0.x, a0.y, a0.z, a0.w, a1.x, a1.y, a1.z, a1.w};
#pragma unroll
      for (int j = 0; j < 8; ++j) {
        float q = qv[j] * s2;
        unsigned short h = f2bf(q);
        qh[c][j] = (short)h;
        ql[c][j] = (short)f2bf(q - bf2f(h));
      }
    }
  }

  float mrun = -__builtin_inff(), lrun = 0.f;
  f32x4 oacc[4];
#pragma unroll
  for (int t = 0; t < 4; ++t) oacc[t] = (f32x4){0.f, 0.f, 0.f, 0.f};

  const uint32_t* wbase = (const uint32_t*)Wf + (size_t)bh * NT * 4096;

  auto stage = [&](int b, int tile) {
    const uint32_t* src = wbase + (size_t)tile * 4096 + (wave * 4) * 256 + lane * 4;
#pragma unroll
    for (int s4 = 0; s4 < 4; ++s4) {
      __builtin_amdgcn_global_load_lds((const gu32*)(src + s4 * 256),
                                       (lu32*)&KV[b][(wave * 4 + s4) * 512], 16, 0, 0);
    }
  };

  auto compute = [&](int b) {
    const short* base = &KV[b][0];
    // S^T = K·Q^T : D row = kv (16t+4lg+r), col = q (lc)
    f32x4 sacc[4];
#pragma unroll
    for (int t = 0; t < 4; ++t) sacc[t] = (f32x4){0.f, 0.f, 0.f, 0.f};
    __builtin_amdgcn_s_setprio(1);
#pragma unroll
    for (int t = 0; t < 4; ++t) {
#pragma unroll
      for (int c = 0; c < 2; ++c) {
        sv8 kf = *(const sv8*)(base + (t * 2 + c) * 512 + lane * 8);
        sacc[t] = mfma_bf16(kf, qh[c], sacc[t]);
        sacc[t] = mfma_bf16(kf, ql[c], sacc[t]);
      }
    }
    __builtin_amdgcn_s_setprio(0);

    // online softmax: lane owns 16 kv values of q-row lc; reduce in-lane + 2 shfl
    float pm = sacc[0][0];
#pragma unroll
    for (int t = 0; t < 4; ++t)
#pragma unroll
      for (int r = 0; r < 4; ++r) pm = fmaxf(pm, sacc[t][r]);
    pm = fmaxf(pm, __shfl_xor(pm, 16));
    pm = fmaxf(pm, __shfl_xor(pm, 32));
    float mnew = fmaxf(mrun, pm);
    float fsc = exp2f(mrun - mnew);
    mrun = mnew;
    float rs = 0.f;
    float p[4][4];
#pragma unroll
    for (int t = 0; t < 4; ++t)
#pragma unroll
      for (int r = 0; r < 4; ++r) {
        float pv = exp2f(sacc[t][r] - mnew);
        p[t][r] = pv; rs += pv;
      }
    rs += __shfl_xor(rs, 16);
    rs += __shfl_xor(rs, 32);
    lrun = lrun * fsc + rs;

    // P -> per-wave LDS, b64 writes, chunk-XOR swizzle (16B granules)
#pragma unroll
    for (int t = 0; t < 4; ++t) {
      uint64_t w = (uint64_t)f2bf(p[t][0])
                 | ((uint64_t)f2bf(p[t][1]) << 16)
                 | ((uint64_t)f2bf(p[t][2]) << 32)
                 | ((uint64_t)f2bf(p[t][3]) << 48);
      int cw = (2 * t + (lg >> 1)) ^ (lc & 7);
      *(uint64_t*)(&Pw[wave][lc * 64 + cw * 8 + 4 * (lg & 1)]) = w;
    }
    // rescale O by this row's factor (broadcast from lane lc==4lg+r)
    float fq[4];
#pragma unroll
    for (int r = 0; r < 4; ++r) fq[r] = __shfl(fsc, 4 * lg + r);
#pragma unroll
    for (int dt = 0; dt < 4; ++dt)
#pragma unroll
      for (int r = 0; r < 4; ++r) oacc[dt][r] *= fq[r];

    asm volatile("s_waitcnt lgkmcnt(0)" ::: "memory");  // P writes landed (same wave)
    sv8 pa[2];
#pragma unroll
    for (int kc = 0; kc < 2; ++kc) {
      int cr = (4 * kc + lg) ^ (lc & 7);
      pa[kc] = *(const sv8*)(&Pw[wave][lc * 64 + cr * 8]);
    }
    __builtin_amdgcn_s_setprio(1);
#pragma unroll
    for (int dt = 0; dt < 4; ++dt)
#pragma unroll
      for (int kc = 0; kc < 2; ++kc) {
        sv8 vb = *(const sv8*)(base + 4096 + (dt * 2 + kc) * 512 + lane * 8);
        oacc[dt] = mfma_bf16(pa[kc], vb, oacc[dt]);
      }
    __builtin_amdgcn_s_setprio(0);
  };

  // T3-lite pipeline: double buffer, counted vmcnt, raw barriers
  stage(0, 0);
  int buf = 0;
  for (int tt = 0; tt < NT - 1; ++tt) {
    stage(buf ^ 1, tt + 1);
    asm volatile("s_waitcnt vmcnt(4)" ::: "memory");  // this tile's 4 loads done
    __builtin_amdgcn_s_barrier();
    asm volatile("" ::: "memory");
    compute(buf);
    asm volatile("s_waitcnt lgkmcnt(0)" ::: "memory");  // reads serviced pre-barrier
    __builtin_amdgcn_s_barrier();
    asm volatile("" ::: "memory");
    buf ^= 1;
  }
  asm volatile("s_waitcnt vmcnt(0)" ::: "memory");
  __builtin_amdgcn_s_barrier();
  asm volatile("" ::: "memory");
  compute(buf);

  // epilogue: normalize + store
  float linv[4];
#pragma unroll
  for (int r = 0; r < 4; ++r) {
    float l = __shfl(lrun, 4 * lg + r);
    linv[r] = 1.0f / l;
  }
  float* op = Og + headoff + (size_t)(q0 + wave * 16) * D_DIM;
#pragma unroll
  for (int dt = 0; dt < 4; ++dt)
#pragma unroll
    for (int r = 0; r < 4; ++r)
      op[(size_t)(4 * lg + r) * D_DIM + 16 * dt + lc] = oacc[dt][r] * linv[r];
}

// ---------------- fallback (round-1 kernel, used only if ws too small) ------
#define DPAD 72
extern "C" __global__ void __launch_bounds__(256)
attn_fwd_v1(const float* __restrict__ Qg, const float* __restrict__ Kg,
            const float* __restrict__ Vg, float* __restrict__ Og) {
  __shared__ unsigned short Khi[64][DPAD];
  __shared__ unsigned short Klo[64][DPAD];
  __shared__ unsigned short Vt[D_DIM][DPAD];
  __shared__ unsigned short Pl[4][16][DPAD];

  const int tid = threadIdx.x, wave = tid >> 6, lane = tid & 63;
  const int bh = blockIdx.y, q0 = blockIdx.x * QB;
  const int lg = lane >> 4, lc = lane & 15, kg = lg << 3;
  const size_t headoff = (size_t)bh * S_LEN * D_DIM;
  const float scale = 0.28867513459481287f;

  sv8 qh[2], ql[2];
  {
    const float* qp = Qg + headoff + (size_t)(q0 + wave * 16 + lc) * D_DIM;
#pragma unroll
    for (int c = 0; c < 2; ++c) {
      const float4 a0 = *reinterpret_cast<const float4*>(qp + c * 32 + kg);
      const float4 a1 = *reinterpret_cast<const float4*>(qp + c * 32 + kg + 4);
      float qv[8] = {a0.x, a0.y, a0.z, a0.w, a1.x, a1.y, a1.z, a1.w};
#pragma unroll
      for (int j = 0; j < 8; ++j) {
        unsigned short h = f2bf(qv[j]);
        qh[c][j] = (short)h;
        ql[c][j] = (short)f2bf(qv[j] - bf2f(h));
      }
    }
  }
  float mrun[4], lrun[4];
  f32x4 oacc[4];
#pragma unroll
  for (int r = 0; r < 4; ++r) { mrun[r] = -__builtin_inff(); lrun[r] = 0.f; }
#pragma unroll
  for (int t = 0; t < 4; ++t) oacc[t] = (f32x4){0.f, 0.f, 0.f, 0.f};

  const int srow = tid >> 2, sd = (tid & 3) << 4;
  const float* kbase = Kg + headoff + sd;
  const float* vbase = Vg + headoff + sd;

  for (int kv0 = 0; kv0 < S_LEN; kv0 += 64) {
    {
      const float* kp = kbase + (size_t)(kv0 + srow) * D_DIM;
      const float* vp = vbase + (size_t)(kv0 + srow) * D_DIM;
#pragma unroll
      for (int i = 0; i < 16; i += 4) {
        float4 kf = *reinterpret_cast<const float4*>(kp + i);
        unsigned short h0 = f2bf(kf.x), h1 = f2bf(kf.y), h2 = f2bf(kf.z), h3 = f2bf(kf.w);
        *reinterpret_cast<uint64_t*>(&Khi[srow][sd + i]) =
            (uint64_t)h0 | ((uint64_t)h1 << 16) | ((uint64_t)h2 << 32) | ((uint64_t)h3 << 48);
        unsigned short l0 = f2bf(kf.x - bf2f(h0)), l1 = f2bf(kf.y - bf2f(h1));
        unsigned short l2 = f2bf(kf.z - bf2f(h2)), l3 = f2bf(kf.w - bf2f(h3));
        *reinterpret_cast<uint64_t*>(&Klo[srow][sd + i]) =
            (uint64_t)l0 | ((uint64_t)l1 << 16) | ((uint64_t)l2 << 32) | ((uint64_t)l3 << 48);
        float4 vf = *reinterpret_cast<const float4*>(vp + i);
        Vt[sd + i + 0][srow] = f2bf(vf.x);
        Vt[sd + i + 1][srow] = f2bf(vf.y);
        Vt[sd + i + 2][srow] = f2bf(vf.z);
        Vt[sd + i + 3][srow] = f2bf(vf.w);
      }
    }
    __syncthreads();
    f32x4 sacc[4];
#pragma unroll
    for (int t = 0; t < 4; ++t) sacc[t] = (f32x4){0.f, 0.f, 0.f, 0.f};
#pragma unroll
    for (int t = 0; t < 4; ++t) {
#pragma unroll
      for (int c = 0; c < 2; ++c) {
        sv8 khv = *reinterpret_cast<const sv8*>(&Khi[t * 16 + lc][c * 32 + kg]);
        sv8 klv = *reinterpret_cast<const sv8*>(&Klo[t * 16 + lc][c * 32 + kg]);
        sacc[t] = mfma_bf16(qh[c], khv, sacc[t]);
        sacc[t] = mfma_bf16(qh[c], klv, sacc[t]);
        sacc[t] = mfma_bf16(ql[c], khv, sacc[t]);
      }
    }
    float p[4][4], pm[4], rs[4];
#pragma unroll
    for (int r = 0; r < 4; ++r) {
      float a = fmaxf(fmaxf(sacc[0][r], sacc[1][r]), fmaxf(sacc[2][r], sacc[3][r]));
      pm[r] = a * scale;
    }
#pragma unroll
    for (int msk = 1; msk < 16; msk <<= 1)
#pragma unroll
      for (int r = 0; r < 4; ++r) pm[r] = fmaxf(pm[r], __shfl_xor(pm[r], msk));
#pragma unroll
    for (int r = 0; r < 4; ++r) {
      float mnew = fmaxf(mrun[r], pm[r]);
      float fsc = __expf(mrun[r] - mnew);
      mrun[r] = mnew;
      float s0 = 0.f;
#pragma unroll
      for (int t = 0; t < 4; ++t) {
        float pv = __expf(sacc[t][r] * scale - mnew);
        p[t][r] = pv; s0 += pv;
      }
      rs[r] = s0;
      lrun[r] *= fsc;
#pragma unroll
      for (int t = 0; t < 4; ++t) oacc[t][r] *= fsc;
    }
#pragma unroll
    for (int msk = 1; msk < 16; msk <<= 1)
#pragma unroll
      for (int r = 0; r < 4; ++r) rs[r] += __shfl_xor(rs[r], msk);
#pragma unroll
    for (int r = 0; r < 4; ++r) lrun[r] += rs[r];
#pragma unroll
    for (int r = 0; r < 4; ++r)
#pragma unroll
      for (int t = 0; t < 4; ++t)
        Pl[wave][lg * 4 + r][t * 16 + lc] = f2bf(p[t][r]);
#pragma unroll
    for (int dt = 0; dt < 4; ++dt) {
#pragma unroll
      for (int kc = 0; kc < 2; ++kc) {
        sv8 pa = *reinterpret_cast<const sv8*>(&Pl[wave][lc][kc * 32 + kg]);
        sv8 vb = *reinterpret_cast<const sv8*>(&Vt[dt * 16 + lc][kc * 32 + kg]);
        oacc[dt] = mfma_bf16(pa, vb, oacc[dt]);
      }
    }
    __syncthreads();
  }
  float* op = Og + headoff + (size_t)(q0 + wave * 16) * D_DIM;
#pragma unroll
  for (int r = 0; r < 4; ++r) {
    float inv = 1.0f / lrun[r];
    int row = lg * 4 + r;
#pragma unroll
    for (int dt = 0; dt < 4; ++dt)
      op[(size_t)row * D_DIM + dt * 16 + lc] = oacc[dt][r] * inv;
  }
}

extern "C" void kernel_launch(void* const* d_in, const int* in_sizes, int n_in,
                              void* d_out, int out_size, void* d_ws, size_t ws_size,
                              hipStream_t stream) {
  const float* Q = (const float*)d_in[0];
  const float* K = (const float*)d_in[1];
  const float* V = (const float*)d_in[2];
  float* O = (float*)d_out;
  const size_t need = (size_t)NBH * NT * TILE_SHORTS * sizeof(short);  // 32 MB
  if (ws_size >= need) {
    prep_kv<<<dim3(NT, NBH), dim3(256), 0, stream>>>(K, V, (unsigned short*)d_ws);
    attn_fwd<<<dim3(S_LEN / QB, NBH), dim3(256), 0, stream>>>(Q, (const unsigned short*)d_ws, O);
  } else {
    attn_fwd_v1<<<dim3(S_LEN / QB, NBH), dim3(256), 0, stream>>>(Q, K, V, O);
  }
}

// Round 3
// 175.171 us; speedup vs baseline: 1.8477x; 1.1111x over previous
//
#include <hip/hip_runtime.h>
#include <hip/hip_bf16.h>
#include <stdint.h>

#define S_LEN 2048
#define D_DIM 64
#define NBH   64              // B*H
#define QB    64              // q rows per block (16 per wave)
#define NT    (S_LEN / 64)    // 32 kv tiles
#define TILE_SHORTS 8192      // 16KB per kv tile: K frags 8KB + V frags 8KB

typedef __bf16 bf8_t __attribute__((ext_vector_type(8)));
typedef short  sv8   __attribute__((ext_vector_type(8)));
typedef float  f32x4 __attribute__((ext_vector_type(4)));
typedef __attribute__((address_space(1))) uint32_t gu32;
typedef __attribute__((address_space(3))) uint32_t lu32;

static __device__ __forceinline__ unsigned short f2bf(float x) {
  union { float f; unsigned int u; } v; v.f = x;
  unsigned int r = v.u + 0x7FFFu + ((v.u >> 16) & 1u);  // RNE
  return (unsigned short)(r >> 16);
}
static __device__ __forceinline__ float bf2f(unsigned short h) {
  union { float f; unsigned int u; } v; v.u = ((unsigned int)h) << 16;
  return v.f;
}
static __device__ __forceinline__ uint32_t cvtpk(float a, float b) {
  union { __hip_bfloat162 h; uint32_t u; } r;
  r.h = __float22bfloat162_rn(make_float2(a, b));   // v_cvt_pk_bf16_f32
  return r.u;
}
static __device__ __forceinline__ f32x4 mfma_bf16(sv8 a, sv8 b, f32x4 c) {
  union { sv8 s; bf8_t b; } ua, ub; ua.s = a; ub.s = b;
  return __builtin_amdgcn_mfma_f32_16x16x32_bf16(ua.b, ub.b, c, 0, 0, 0);
}

// ---------------- pre-pass: K,V fp32 -> bf16 MFMA fragment order in d_ws ----
extern "C" __global__ void __launch_bounds__(256)
prep_kv(const float* __restrict__ Kg, const float* __restrict__ Vg,
        unsigned short* __restrict__ Wf) {
  const int tile = blockIdx.x, bh = blockIdx.y, tid = threadIdx.x;
  const size_t in_head = (size_t)bh * S_LEN * D_DIM;
  unsigned short* out = Wf + (size_t)(bh * NT + tile) * TILE_SHORTS;

#pragma unroll
  for (int k8 = 0; k8 < 2; ++k8) {     // K slots
    int s = tid + 256 * k8;
    int chunk = s >> 6, lane = s & 63;
    int t = chunk >> 1, c = chunk & 1, lc = lane & 15, lg = lane >> 4;
    const float* p = Kg + in_head + (size_t)(tile * 64 + 16 * t + lc) * D_DIM + 32 * c + 8 * lg;
    float4 f0 = *(const float4*)p;
    float4 f1 = *(const float4*)(p + 4);
    uint4 w;
    w.x = cvtpk(f0.x, f0.y);
    w.y = cvtpk(f0.z, f0.w);
    w.z = cvtpk(f1.x, f1.y);
    w.w = cvtpk(f1.z, f1.w);
    *(uint4*)(out + (size_t)s * 8) = w;
  }
#pragma unroll
  for (int k8 = 0; k8 < 2; ++k8) {     // V slots (transpose)
    int s = tid + 256 * k8;
    int chunk = s >> 6, lane = s & 63;
    int dt = chunk >> 1, kc = chunk & 1, lc = lane & 15, lg = lane >> 4;
    const float* p = Vg + in_head + (size_t)(tile * 64 + 32 * kc + 8 * lg) * D_DIM + 16 * dt + lc;
    uint4 w;
    w.x = cvtpk(p[0 * D_DIM], p[1 * D_DIM]);
    w.y = cvtpk(p[2 * D_DIM], p[3 * D_DIM]);
    w.z = cvtpk(p[4 * D_DIM], p[5 * D_DIM]);
    w.w = cvtpk(p[6 * D_DIM], p[7 * D_DIM]);
    *(uint4*)(out + (size_t)(512 + s) * 8) = w;
  }
}

// ---------------- main attention kernel -------------------------------------
extern "C" __global__ void __launch_bounds__(256)
attn_fwd(const float* __restrict__ Qg, const unsigned short* __restrict__ Wf,
         float* __restrict__ Og) {
  __shared__ short KV[2][TILE_SHORTS];  // double-buffered tile (32KB)
  __shared__ short Pw[4][1024];         // per-wave P, chunk-XOR swizzled (8KB)

  const int tid = threadIdx.x, wave = tid >> 6, lane = tid & 63;
  const int lg = lane >> 4, lc = lane & 15;
  const int bh = blockIdx.x, q0 = blockIdx.y * QB;   // bh on x: XCD = bh%8
  const size_t headoff = (size_t)bh * S_LEN * D_DIM;

  // Q B-fragments, pre-scaled by (1/sqrt(12))*log2(e), hi/lo split
  const float s2 = 0.28867513459481287f * 1.44269504088896340f;
  sv8 qh[2], ql[2];
  {
    const float* qp = Qg + headoff + (size_t)(q0 + wave * 16 + lc) * D_DIM;
#pragma unroll
    for (int c = 0; c < 2; ++c) {
      float4 a0 = *(const float4*)(qp + c * 32 + 8 * lg);
      float4 a1 = *(const float4*)(qp + c * 32 + 8 * lg + 4);
      float qv[8] = {a0.x, a0.y, a0.z, a0.w, a1.x, a1.y, a1.z, a1.w};
#pragma unroll
      for (int j = 0; j < 8; ++j) {
        float q = qv[j] * s2;
        unsigned short h = f2bf(q);
        qh[c][j] = (short)h;
        ql[c][j] = (short)f2bf(q - bf2f(h));
      }
    }
  }

  float mrun = -__builtin_inff(), lrun = 0.f;
  f32x4 oacc[4];
#pragma unroll
  for (int t = 0; t < 4; ++t) oacc[t] = (f32x4){0.f, 0.f, 0.f, 0.f};

  // P LDS addresses — tile-invariant, hoisted
  const int lcx = lc & 7, lgh = lg >> 1, lgl = lg & 1;
  uint64_t* pwa[4];
#pragma unroll
  for (int t = 0; t < 4; ++t)
    pwa[t] = (uint64_t*)&Pw[wave][lc * 64 + (((2 * t + lgh) ^ lcx) * 8) + 4 * lgl];
  const sv8* pra[2];
#pragma unroll
  for (int kc = 0; kc < 2; ++kc)
    pra[kc] = (const sv8*)&Pw[wave][lc * 64 + (((4 * kc + lg) ^ lcx) * 8)];

  // running staging pointer (advances one 16KB tile per stage)
  const gu32* sptr = (const gu32*)((const uint32_t*)Wf + (size_t)bh * NT * 4096)
                   + wave * 1024 + lane * 4;

  auto stage = [&](int buf) {
    lu32* dst = (lu32*)&KV[buf][wave * 2048];
#pragma unroll
    for (int s4 = 0; s4 < 4; ++s4)
      __builtin_amdgcn_global_load_lds(sptr + s4 * 256, dst + s4 * 256, 16, 0, 0);
    sptr += 4096;
  };

  auto compute = [&](const short* base) {
    f32x4 sacc[4];
#pragma unroll
    for (int t = 0; t < 4; ++t) sacc[t] = (f32x4){0.f, 0.f, 0.f, 0.f};
    __builtin_amdgcn_s_setprio(1);
#pragma unroll
    for (int t = 0; t < 4; ++t) {
#pragma unroll
      for (int c = 0; c < 2; ++c) {
        sv8 kf = *(const sv8*)(base + (t * 2 + c) * 512 + lane * 8);
        sacc[t] = mfma_bf16(kf, qh[c], sacc[t]);
        sacc[t] = mfma_bf16(kf, ql[c], sacc[t]);
      }
    }
    __builtin_amdgcn_s_setprio(0);

    // row max (lane owns 16 kv of q-row lc) + cross-lane over the 4 groups
    float mt[4];
#pragma unroll
    for (int t = 0; t < 4; ++t)
      mt[t] = fmaxf(fmaxf(sacc[t][0], sacc[t][1]), fmaxf(sacc[t][2], sacc[t][3]));
    float pm = fmaxf(fmaxf(mt[0], mt[1]), fmaxf(mt[2], mt[3]));
    pm = fmaxf(pm, __shfl_xor(pm, 16));
    pm = fmaxf(pm, __shfl_xor(pm, 32));

    // T13 defer-rescale: skip when tile max is within 8 log2-units of running max
    const bool noresc = __all(pm - mrun <= 8.0f);
    float fsc = 1.0f;
    if (!noresc) {
      float mnew = fmaxf(mrun, pm);
      fsc = exp2f(mrun - mnew);
      mrun = mnew;
    }
    float p[4][4], rt[4];
#pragma unroll
    for (int t = 0; t < 4; ++t) {
#pragma unroll
      for (int r = 0; r < 4; ++r) p[t][r] = exp2f(sacc[t][r] - mrun);
      rt[t] = (p[t][0] + p[t][1]) + (p[t][2] + p[t][3]);
    }
    float rs = (rt[0] + rt[1]) + (rt[2] + rt[3]);
    rs += __shfl_xor(rs, 16);
    rs += __shfl_xor(rs, 32);
    if (!noresc) {
      lrun = lrun * fsc + rs;
      float fq[4];
#pragma unroll
      for (int r = 0; r < 4; ++r) fq[r] = __shfl(fsc, 4 * lg + r);
#pragma unroll
      for (int dt = 0; dt < 4; ++dt)
#pragma unroll
        for (int r = 0; r < 4; ++r) oacc[dt][r] *= fq[r];
    } else {
      lrun += rs;
    }

    // P -> per-wave LDS via packed cvt (addresses hoisted)
#pragma unroll
    for (int t = 0; t < 4; ++t) {
      uint32_t w0 = cvtpk(p[t][0], p[t][1]);
      uint32_t w1 = cvtpk(p[t][2], p[t][3]);
      *pwa[t] = (uint64_t)w0 | ((uint64_t)w1 << 32);
    }
    asm volatile("s_waitcnt lgkmcnt(0)" ::: "memory");
    __builtin_amdgcn_sched_barrier(0);
    sv8 pa0 = *pra[0];
    sv8 pa1 = *pra[1];
    __builtin_amdgcn_s_setprio(1);
#pragma unroll
    for (int dt = 0; dt < 4; ++dt) {
      sv8 vb0 = *(const sv8*)(base + 4096 + (dt * 2 + 0) * 512 + lane * 8);
      sv8 vb1 = *(const sv8*)(base + 4096 + (dt * 2 + 1) * 512 + lane * 8);
      oacc[dt] = mfma_bf16(pa0, vb0, oacc[dt]);
      oacc[dt] = mfma_bf16(pa1, vb1, oacc[dt]);
    }
    __builtin_amdgcn_s_setprio(0);
  };

  // double-buffered pipeline, 2 tiles/iter, compile-time buffer indices
  stage(0);
  for (int it = 0; it < NT / 2 - 1; ++it) {
    stage(1);
    asm volatile("s_waitcnt vmcnt(4)" ::: "memory");
    __builtin_amdgcn_s_barrier();
    asm volatile("" ::: "memory");
    compute(&KV[0][0]);
    asm volatile("s_waitcnt lgkmcnt(0)" ::: "memory");
    __builtin_amdgcn_s_barrier();
    asm volatile("" ::: "memory");
    stage(0);
    asm volatile("s_waitcnt vmcnt(4)" ::: "memory");
    __builtin_amdgcn_s_barrier();
    asm volatile("" ::: "memory");
    compute(&KV[1][0]);
    asm volatile("s_waitcnt lgkmcnt(0)" ::: "memory");
    __builtin_amdgcn_s_barrier();
    asm volatile("" ::: "memory");
  }
  stage(1);                                        // tile NT-1
  asm volatile("s_waitcnt vmcnt(4)" ::: "memory"); // tile NT-2 ready
  __builtin_amdgcn_s_barrier();
  asm volatile("" ::: "memory");
  compute(&KV[0][0]);
  asm volatile("s_waitcnt vmcnt(0)" ::: "memory"); // tile NT-1 ready
  __builtin_amdgcn_s_barrier();
  asm volatile("" ::: "memory");
  compute(&KV[1][0]);

  // epilogue: normalize + store
  float linv[4];
#pragma unroll
  for (int r = 0; r < 4; ++r) {
    float l = __shfl(lrun, 4 * lg + r);
    linv[r] = 1.0f / l;
  }
  float* op = Og + headoff + (size_t)(q0 + wave * 16) * D_DIM;
#pragma unroll
  for (int dt = 0; dt < 4; ++dt)
#pragma unroll
    for (int r = 0; r < 4; ++r)
      op[(size_t)(4 * lg + r) * D_DIM + 16 * dt + lc] = oacc[dt][r] * linv[r];
}

// ---------------- fallback (round-1 kernel, used only if ws too small) ------
#define DPAD 72
extern "C" __global__ void __launch_bounds__(256)
attn_fwd_v1(const float* __restrict__ Qg, const float* __restrict__ Kg,
            const float* __restrict__ Vg, float* __restrict__ Og) {
  __shared__ unsigned short Khi[64][DPAD];
  __shared__ unsigned short Klo[64][DPAD];
  __shared__ unsigned short Vt[D_DIM][DPAD];
  __shared__ unsigned short Pl[4][16][DPAD];

  const int tid = threadIdx.x, wave = tid >> 6, lane = tid & 63;
  const int bh = blockIdx.y, q0 = blockIdx.x * QB;
  const int lg = lane >> 4, lc = lane & 15, kg = lg << 3;
  const size_t headoff = (size_t)bh * S_LEN * D_DIM;
  const float scale = 0.28867513459481287f;

  sv8 qh[2], ql[2];
  {
    const float* qp = Qg + headoff + (size_t)(q0 + wave * 16 + lc) * D_DIM;
#pragma unroll
    for (int c = 0; c < 2; ++c) {
      const float4 a0 = *reinterpret_cast<const float4*>(qp + c * 32 + kg);
      const float4 a1 = *reinterpret_cast<const float4*>(qp + c * 32 + kg + 4);
      float qv[8] = {a0.x, a0.y, a0.z, a0.w, a1.x, a1.y, a1.z, a1.w};
#pragma unroll
      for (int j = 0; j < 8; ++j) {
        unsigned short h = f2bf(qv[j]);
        qh[c][j] = (short)h;
        ql[c][j] = (short)f2bf(qv[j] - bf2f(h));
      }
    }
  }
  float mrun[4], lrun[4];
  f32x4 oacc[4];
#pragma unroll
  for (int r = 0; r < 4; ++r) { mrun[r] = -__builtin_inff(); lrun[r] = 0.f; }
#pragma unroll
  for (int t = 0; t < 4; ++t) oacc[t] = (f32x4){0.f, 0.f, 0.f, 0.f};

  const int srow = tid >> 2, sd = (tid & 3) << 4;
  const float* kbase = Kg + headoff + sd;
  const float* vbase = Vg + headoff + sd;

  for (int kv0 = 0; kv0 < S_LEN; kv0 += 64) {
    {
      const float* kp = kbase + (size_t)(kv0 + srow) * D_DIM;
      const float* vp = vbase + (size_t)(kv0 + srow) * D_DIM;
#pragma unroll
      for (int i = 0; i < 16; i += 4) {
        float4 kf = *reinterpret_cast<const float4*>(kp + i);
        unsigned short h0 = f2bf(kf.x), h1 = f2bf(kf.y), h2 = f2bf(kf.z), h3 = f2bf(kf.w);
        *reinterpret_cast<uint64_t*>(&Khi[srow][sd + i]) =
            (uint64_t)h0 | ((uint64_t)h1 << 16) | ((uint64_t)h2 << 32) | ((uint64_t)h3 << 48);
        unsigned short l0 = f2bf(kf.x - bf2f(h0)), l1 = f2bf(kf.y - bf2f(h1));
        unsigned short l2 = f2bf(kf.z - bf2f(h2)), l3 = f2bf(kf.w - bf2f(h3));
        *reinterpret_cast<uint64_t*>(&Klo[srow][sd + i]) =
            (uint64_t)l0 | ((uint64_t)l1 << 16) | ((uint64_t)l2 << 32) | ((uint64_t)l3 << 48);
        float4 vf = *reinterpret_cast<const float4*>(vp + i);
        Vt[sd + i + 0][srow] = f2bf(vf.x);
        Vt[sd + i + 1][srow] = f2bf(vf.y);
        Vt[sd + i + 2][srow] = f2bf(vf.z);
        Vt[sd + i + 3][srow] = f2bf(vf.w);
      }
    }
    __syncthreads();
    f32x4 sacc[4];
#pragma unroll
    for (int t = 0; t < 4; ++t) sacc[t] = (f32x4){0.f, 0.f, 0.f, 0.f};
#pragma unroll
    for (int t = 0; t < 4; ++t) {
#pragma unroll
      for (int c = 0; c < 2; ++c) {
        sv8 khv = *reinterpret_cast<const sv8*>(&Khi[t * 16 + lc][c * 32 + kg]);
        sv8 klv = *reinterpret_cast<const sv8*>(&Klo[t * 16 + lc][c * 32 + kg]);
        sacc[t] = mfma_bf16(qh[c], khv, sacc[t]);
        sacc[t] = mfma_bf16(qh[c], klv, sacc[t]);
        sacc[t] = mfma_bf16(ql[c], khv, sacc[t]);
      }
    }
    float p[4][4], pm[4], rs[4];
#pragma unroll
    for (int r = 0; r < 4; ++r) {
      float a = fmaxf(fmaxf(sacc[0][r], sacc[1][r]), fmaxf(sacc[2][r], sacc[3][r]));
      pm[r] = a * scale;
    }
#pragma unroll
    for (int msk = 1; msk < 16; msk <<= 1)
#pragma unroll
      for (int r = 0; r < 4; ++r) pm[r] = fmaxf(pm[r], __shfl_xor(pm[r], msk));
#pragma unroll
    for (int r = 0; r < 4; ++r) {
      float mnew = fmaxf(mrun[r], pm[r]);
      float fsc = __expf(mrun[r] - mnew);
      mrun[r] = mnew;
      float s0 = 0.f;
#pragma unroll
      for (int t = 0; t < 4; ++t) {
        float pv = __expf(sacc[t][r] * scale - mnew);
        p[t][r] = pv; s0 += pv;
      }
      rs[r] = s0;
      lrun[r] *= fsc;
#pragma unroll
      for (int t = 0; t < 4; ++t) oacc[t][r] *= fsc;
    }
#pragma unroll
    for (int msk = 1; msk < 16; msk <<= 1)
#pragma unroll
      for (int r = 0; r < 4; ++r) rs[r] += __shfl_xor(rs[r], msk);
#pragma unroll
    for (int r = 0; r < 4; ++r) lrun[r] += rs[r];
#pragma unroll
    for (int r = 0; r < 4; ++r)
#pragma unroll
      for (int t = 0; t < 4; ++t)
        Pl[wave][lg * 4 + r][t * 16 + lc] = f2bf(p[t][r]);
#pragma unroll
    for (int dt = 0; dt < 4; ++dt) {
#pragma unroll
      for (int kc = 0; kc < 2; ++kc) {
        sv8 pa = *reinterpret_cast<const sv8*>(&Pl[wave][lc][kc * 32 + kg]);
        sv8 vb = *reinterpret_cast<const sv8*>(&Vt[dt * 16 + lc][kc * 32 + kg]);
        oacc[dt] = mfma_bf16(pa, vb, oacc[dt]);
      }
    }
    __syncthreads();
  }
  float* op = Og + headoff + (size_t)(q0 + wave * 16) * D_DIM;
#pragma unroll
  for (int r = 0; r < 4; ++r) {
    float inv = 1.0f / lrun[r];
    int row = lg * 4 + r;
#pragma unroll
    for (int dt = 0; dt < 4; ++dt)
      op[(size_t)row * D_DIM + dt * 16 + lc] = oacc[dt][r] * inv;
  }
}

extern "C" void kernel_launch(void* const* d_in, const int* in_sizes, int n_in,
                              void* d_out, int out_size, void* d_ws, size_t ws_size,
                              hipStream_t stream) {
  const float* Q = (const float*)d_in[0];
  const float* K = (const float*)d_in[1];
  const float* V = (const float*)d_in[2];
  float* O = (float*)d_out;
  const size_t need = (size_t)NBH * NT * TILE_SHORTS * sizeof(short);  // 32 MB
  if (ws_size >= need) {
    prep_kv<<<dim3(NT, NBH), dim3(256), 0, stream>>>(K, V, (unsigned short*)d_ws);
    attn_fwd<<<dim3(NBH, S_LEN / QB), dim3(256), 0, stream>>>(Q, (const unsigned short*)d_ws, O);
  } else {
    attn_fwd_v1<<<dim3(S_LEN / QB, NBH), dim3(256), 0, stream>>>(Q, K, V, O);
  }
}

// Round 4
// 173.761 us; speedup vs baseline: 1.8627x; 1.0081x over previous
//
#include <hip/hip_runtime.h>
#include <hip/hip_bf16.h>
#include <stdint.h>

#define S_LEN 2048
#define D_DIM 64
#define NBH   64              // B*H
#define QB    64              // q rows per block (16 per wave)
#define NT    (S_LEN / 64)    // 32 kv tiles
#define TILE_SHORTS 8192      // 16KB per kv tile: K frags 8KB + V frags 8KB

typedef __bf16 bf8_t __attribute__((ext_vector_type(8)));
typedef short  sv8   __attribute__((ext_vector_type(8)));
typedef float  f32x4 __attribute__((ext_vector_type(4)));
typedef __attribute__((address_space(1))) uint32_t gu32;
typedef __attribute__((address_space(3))) uint32_t lu32;

static __device__ __forceinline__ unsigned short f2bf(float x) {
  union { float f; unsigned int u; } v; v.f = x;
  unsigned int r = v.u + 0x7FFFu + ((v.u >> 16) & 1u);  // RNE
  return (unsigned short)(r >> 16);
}
static __device__ __forceinline__ float bf2f(unsigned short h) {
  union { float f; unsigned int u; } v; v.u = ((unsigned int)h) << 16;
  return v.f;
}
static __device__ __forceinline__ uint32_t cvtpk(float a, float b) {
  union { __hip_bfloat162 h; uint32_t u; } r;
  r.h = __float22bfloat162_rn(make_float2(a, b));   // v_cvt_pk_bf16_f32
  return r.u;
}
static __device__ __forceinline__ f32x4 mfma_bf16(sv8 a, sv8 b, f32x4 c) {
  union { sv8 s; bf8_t b; } ua, ub; ua.s = a; ub.s = b;
  return __builtin_amdgcn_mfma_f32_16x16x32_bf16(ua.b, ub.b, c, 0, 0, 0);
}

// ---------------- pre-pass: K,V fp32 -> bf16 MFMA fragment order in d_ws ----
// K slots 0..511, V slots 512..1023 (granule = 16B per (chunk,lane)).
// V granules for lanes>=32 have their 8B halves swapped: the in-kernel
// bpermute P-exchange delivers those lanes' A-fragments with k-slots j^4;
// swapping V's halves applies the same permutation to B so it cancels.
extern "C" __global__ void __launch_bounds__(256)
prep_kv(const float* __restrict__ Kg, const float* __restrict__ Vg,
        unsigned short* __restrict__ Wf) {
  const int tile = blockIdx.x, bh = blockIdx.y, tid = threadIdx.x;
  const size_t in_head = (size_t)bh * S_LEN * D_DIM;
  unsigned short* out = Wf + (size_t)(bh * NT + tile) * TILE_SHORTS;

#pragma unroll
  for (int k8 = 0; k8 < 2; ++k8) {     // K slots
    int s = tid + 256 * k8;
    int chunk = s >> 6, lane = s & 63;
    int t = chunk >> 1, c = chunk & 1, lc = lane & 15, lg = lane >> 4;
    const float* p = Kg + in_head + (size_t)(tile * 64 + 16 * t + lc) * D_DIM + 32 * c + 8 * lg;
    float4 f0 = *(const float4*)p;
    float4 f1 = *(const float4*)(p + 4);
    uint4 w;
    w.x = cvtpk(f0.x, f0.y);
    w.y = cvtpk(f0.z, f0.w);
    w.z = cvtpk(f1.x, f1.y);
    w.w = cvtpk(f1.z, f1.w);
    *(uint4*)(out + (size_t)s * 8) = w;
  }
#pragma unroll
  for (int k8 = 0; k8 < 2; ++k8) {     // V slots (transpose)
    int s = tid + 256 * k8;
    int chunk = s >> 6, lane = s & 63;
    int dt = chunk >> 1, kc = chunk & 1, lc = lane & 15, lg = lane >> 4;
    const float* p = Vg + in_head + (size_t)(tile * 64 + 32 * kc + 8 * lg) * D_DIM + 16 * dt + lc;
    uint32_t h0 = cvtpk(p[0 * D_DIM], p[1 * D_DIM]);
    uint32_t h1 = cvtpk(p[2 * D_DIM], p[3 * D_DIM]);
    uint32_t h2 = cvtpk(p[4 * D_DIM], p[5 * D_DIM]);
    uint32_t h3 = cvtpk(p[6 * D_DIM], p[7 * D_DIM]);
    uint4 w;
    if (lane >= 32) { w.x = h2; w.y = h3; w.z = h0; w.w = h1; }
    else            { w.x = h0; w.y = h1; w.z = h2; w.w = h3; }
    *(uint4*)(out + (size_t)(512 + s) * 8) = w;
  }
}

// ---------------- main attention kernel -------------------------------------
extern "C" __global__ void __launch_bounds__(256)
attn_fwd(const float* __restrict__ Qg, const unsigned short* __restrict__ Wf,
         float* __restrict__ Og) {
  __shared__ short KV[2][TILE_SHORTS];  // double-buffered tile (32KB total)

  const int tid = threadIdx.x, wave = tid >> 6, lane = tid & 63;
  const int lg = lane >> 4, lc = lane & 15;
  const int bh = blockIdx.x, q0 = blockIdx.y * QB;   // bh on x: XCD = bh%8
  const size_t headoff = (size_t)bh * S_LEN * D_DIM;

  // Q B-fragments, pre-scaled by (1/sqrt(12))*log2(e), hi/lo split
  const float s2 = 0.28867513459481287f * 1.44269504088896340f;
  sv8 qh[2], ql[2];
  {
    const float* qp = Qg + headoff + (size_t)(q0 + wave * 16 + lc) * D_DIM;
#pragma unroll
    for (int c = 0; c < 2; ++c) {
      float4 a0 = *(const float4*)(qp + c * 32 + 8 * lg);
      float4 a1 = *(const float4*)(qp + c * 32 + 8 * lg + 4);
      float qv[8] = {a0.x, a0.y, a0.z, a0.w, a1.x, a1.y, a1.z, a1.w};
#pragma unroll
      for (int j = 0; j < 8; ++j) {
        float q = qv[j] * s2;
        unsigned short h = f2bf(q);
        qh[c][j] = (short)h;
        ql[c][j] = (short)f2bf(q - bf2f(h));
      }
    }
  }

  float mrun = -__builtin_inff(), lrun = 0.f;
  f32x4 oacc[4];
#pragma unroll
  for (int t = 0; t < 4; ++t) oacc[t] = (f32x4){0.f, 0.f, 0.f, 0.f};

  // bpermute exchange constants (hoisted):
  // round A srcs xor {0,48,48,0}, round B srcs xor {16,32,32,16} per lg
  const int addrA = (lane ^ (((lg == 1) || (lg == 2)) ? 48 : 0)) << 2;
  const int addrB = (lane ^ (((lg == 0) || (lg == 3)) ? 16 : 32)) << 2;
  const bool godd = (lg & 1);

  // running staging pointer (advances one 16KB tile per stage)
  const gu32* sptr = (const gu32*)((const uint32_t*)Wf + (size_t)bh * NT * 4096)
                   + wave * 1024 + lane * 4;

  auto stage = [&](int buf) {
    lu32* dst = (lu32*)&KV[buf][wave * 2048];
#pragma unroll
    for (int s4 = 0; s4 < 4; ++s4)
      __builtin_amdgcn_global_load_lds(sptr + s4 * 256, dst + s4 * 256, 16, 0, 0);
    sptr += 4096;
  };

  auto compute = [&](const short* base) {
    f32x4 sacc[4];
#pragma unroll
    for (int t = 0; t < 4; ++t) sacc[t] = (f32x4){0.f, 0.f, 0.f, 0.f};
    __builtin_amdgcn_s_setprio(1);
#pragma unroll
    for (int t = 0; t < 4; ++t) {
#pragma unroll
      for (int c = 0; c < 2; ++c) {
        sv8 kf = *(const sv8*)(base + (t * 2 + c) * 512 + lane * 8);
        sacc[t] = mfma_bf16(kf, qh[c], sacc[t]);
        sacc[t] = mfma_bf16(kf, ql[c], sacc[t]);
      }
    }
    __builtin_amdgcn_s_setprio(0);

    // row max: left-assoc chains (v_max3-fusable), then 2 cross-lane hops
    float mt0 = fmaxf(fmaxf(fmaxf(sacc[0][0], sacc[0][1]), sacc[0][2]), sacc[0][3]);
    float mt1 = fmaxf(fmaxf(fmaxf(sacc[1][0], sacc[1][1]), sacc[1][2]), sacc[1][3]);
    float mt2 = fmaxf(fmaxf(fmaxf(sacc[2][0], sacc[2][1]), sacc[2][2]), sacc[2][3]);
    float mt3 = fmaxf(fmaxf(fmaxf(sacc[3][0], sacc[3][1]), sacc[3][2]), sacc[3][3]);
    float pm = fmaxf(fmaxf(fmaxf(mt0, mt1), mt2), mt3);
    pm = fmaxf(pm, __shfl_xor(pm, 16));
    pm = fmaxf(pm, __shfl_xor(pm, 32));

    // T13 defer-rescale
    const bool noresc = __all(pm - mrun <= 8.0f);
    float fsc = 1.0f;
    if (!noresc) {
      float mnew = fmaxf(mrun, pm);
      fsc = exp2f(mrun - mnew);
      mrun = mnew;
    }
    float p[4][4], rt[4];
#pragma unroll
    for (int t = 0; t < 4; ++t) {
#pragma unroll
      for (int r = 0; r < 4; ++r) p[t][r] = exp2f(sacc[t][r] - mrun);
      rt[t] = (p[t][0] + p[t][1]) + (p[t][2] + p[t][3]);
    }
    float rs = (rt[0] + rt[1]) + (rt[2] + rt[3]);
    rs += __shfl_xor(rs, 16);
    rs += __shfl_xor(rs, 32);
    if (!noresc) {
      lrun = lrun * fsc + rs;
      float fq[4];
#pragma unroll
      for (int r = 0; r < 4; ++r) fq[r] = __shfl(fsc, 4 * lg + r);
#pragma unroll
      for (int dt = 0; dt < 4; ++dt)
#pragma unroll
        for (int r = 0; r < 4; ++r) oacc[dt][r] *= fq[r];
    } else {
      lrun += rs;
    }

    // pack P to bf16 pairs: w[t][0]=(kv 16t+4lg, +1), w[t][1]=(kv 16t+4lg+2, +3)
    uint32_t w[4][2];
#pragma unroll
    for (int t = 0; t < 4; ++t) {
      w[t][0] = cvtpk(p[t][0], p[t][1]);
      w[t][1] = cvtpk(p[t][2], p[t][3]);
    }

    // in-register P redistribution: 2 bijective bpermute rounds per kc.
    // round A: src contributes w[2kc + (g&1)]; round B: w[2kc + !(g&1)].
    // lanes>=32 receive k-slots j^4 — cancelled by prep_kv's V half-swap.
    sv8 pa[2];
#pragma unroll
    for (int kc = 0; kc < 2; ++kc) {
      uint32_t aLo = godd ? w[2 * kc + 1][0] : w[2 * kc][0];
      uint32_t aHi = godd ? w[2 * kc + 1][1] : w[2 * kc][1];
      uint32_t bLo = godd ? w[2 * kc][0]     : w[2 * kc + 1][0];
      uint32_t bHi = godd ? w[2 * kc][1]     : w[2 * kc + 1][1];
      union { int i[4]; sv8 s; } pu;
      pu.i[0] = __builtin_amdgcn_ds_bpermute(addrA, (int)aLo);
      pu.i[1] = __builtin_amdgcn_ds_bpermute(addrA, (int)aHi);
      pu.i[2] = __builtin_amdgcn_ds_bpermute(addrB, (int)bLo);
      pu.i[3] = __builtin_amdgcn_ds_bpermute(addrB, (int)bHi);
      pa[kc] = pu.s;
    }

    __builtin_amdgcn_s_setprio(1);
#pragma unroll
    for (int dt = 0; dt < 4; ++dt) {
      sv8 vb0 = *(const sv8*)(base + 4096 + (dt * 2 + 0) * 512 + lane * 8);
      sv8 vb1 = *(const sv8*)(base + 4096 + (dt * 2 + 1) * 512 + lane * 8);
      oacc[dt] = mfma_bf16(pa[0], vb0, oacc[dt]);
      oacc[dt] = mfma_bf16(pa[1], vb1, oacc[dt]);
    }
    __builtin_amdgcn_s_setprio(0);
  };

  // double-buffered pipeline, 2 tiles/iter, compile-time buffer indices
  stage(0);
  for (int it = 0; it < NT / 2 - 1; ++it) {
    stage(1);
    asm volatile("s_waitcnt vmcnt(4)" ::: "memory");
    __builtin_amdgcn_s_barrier();
    asm volatile("" ::: "memory");
    compute(&KV[0][0]);
    asm volatile("s_waitcnt lgkmcnt(0)" ::: "memory");
    __builtin_amdgcn_s_barrier();
    asm volatile("" ::: "memory");
    stage(0);
    asm volatile("s_waitcnt vmcnt(4)" ::: "memory");
    __builtin_amdgcn_s_barrier();
    asm volatile("" ::: "memory");
    compute(&KV[1][0]);
    asm volatile("s_waitcnt lgkmcnt(0)" ::: "memory");
    __builtin_amdgcn_s_barrier();
    asm volatile("" ::: "memory");
  }
  stage(1);                                        // tile NT-1
  asm volatile("s_waitcnt vmcnt(4)" ::: "memory"); // tile NT-2 ready
  __builtin_amdgcn_s_barrier();
  asm volatile("" ::: "memory");
  compute(&KV[0][0]);
  asm volatile("s_waitcnt vmcnt(0)" ::: "memory"); // tile NT-1 ready
  __builtin_amdgcn_s_barrier();
  asm volatile("" ::: "memory");
  compute(&KV[1][0]);

  // epilogue: normalize + store
  float linv[4];
#pragma unroll
  for (int r = 0; r < 4; ++r) {
    float l = __shfl(lrun, 4 * lg + r);
    linv[r] = 1.0f / l;
  }
  float* op = Og + headoff + (size_t)(q0 + wave * 16) * D_DIM;
#pragma unroll
  for (int dt = 0; dt < 4; ++dt)
#pragma unroll
    for (int r = 0; r < 4; ++r)
      op[(size_t)(4 * lg + r) * D_DIM + 16 * dt + lc] = oacc[dt][r] * linv[r];
}

// ---------------- fallback (round-1 kernel, used only if ws too small) ------
#define DPAD 72
extern "C" __global__ void __launch_bounds__(256)
attn_fwd_v1(const float* __restrict__ Qg, const float* __restrict__ Kg,
            const float* __restrict__ Vg, float* __restrict__ Og) {
  __shared__ unsigned short Khi[64][DPAD];
  __shared__ unsigned short Klo[64][DPAD];
  __shared__ unsigned short Vt[D_DIM][DPAD];
  __shared__ unsigned short Pl[4][16][DPAD];

  const int tid = threadIdx.x, wave = tid >> 6, lane = tid & 63;
  const int bh = blockIdx.y, q0 = blockIdx.x * QB;
  const int lg = lane >> 4, lc = lane & 15, kg = lg << 3;
  const size_t headoff = (size_t)bh * S_LEN * D_DIM;
  const float scale = 0.28867513459481287f;

  sv8 qh[2], ql[2];
  {
    const float* qp = Qg + headoff + (size_t)(q0 + wave * 16 + lc) * D_DIM;
#pragma unroll
    for (int c = 0; c < 2; ++c) {
      const float4 a0 = *reinterpret_cast<const float4*>(qp + c * 32 + kg);
      const float4 a1 = *reinterpret_cast<const float4*>(qp + c * 32 + kg + 4);
      float qv[8] = {a0.x, a0.y, a0.z, a0.w, a1.x, a1.y, a1.z, a1.w};
#pragma unroll
      for (int j = 0; j < 8; ++j) {
        unsigned short h = f2bf(qv[j]);
        qh[c][j] = (short)h;
        ql[c][j] = (short)f2bf(qv[j] - bf2f(h));
      }
    }
  }
  float mrun[4], lrun[4];
  f32x4 oacc[4];
#pragma unroll
  for (int r = 0; r < 4; ++r) { mrun[r] = -__builtin_inff(); lrun[r] = 0.f; }
#pragma unroll
  for (int t = 0; t < 4; ++t) oacc[t] = (f32x4){0.f, 0.f, 0.f, 0.f};

  const int srow = tid >> 2, sd = (tid & 3) << 4;
  const float* kbase = Kg + headoff + sd;
  const float* vbase = Vg + headoff + sd;

  for (int kv0 = 0; kv0 < S_LEN; kv0 += 64) {
    {
      const float* kp = kbase + (size_t)(kv0 + srow) * D_DIM;
      const float* vp = vbase + (size_t)(kv0 + srow) * D_DIM;
#pragma unroll
      for (int i = 0; i < 16; i += 4) {
        float4 kf = *reinterpret_cast<const float4*>(kp + i);
        unsigned short h0 = f2bf(kf.x), h1 = f2bf(kf.y), h2 = f2bf(kf.z), h3 = f2bf(kf.w);
        *reinterpret_cast<uint64_t*>(&Khi[srow][sd + i]) =
            (uint64_t)h0 | ((uint64_t)h1 << 16) | ((uint64_t)h2 << 32) | ((uint64_t)h3 << 48);
        unsigned short l0 = f2bf(kf.x - bf2f(h0)), l1 = f2bf(kf.y - bf2f(h1));
        unsigned short l2 = f2bf(kf.z - bf2f(h2)), l3 = f2bf(kf.w - bf2f(h3));
        *reinterpret_cast<uint64_t*>(&Klo[srow][sd + i]) =
            (uint64_t)l0 | ((uint64_t)l1 << 16) | ((uint64_t)l2 << 32) | ((uint64_t)l3 << 48);
        float4 vf = *reinterpret_cast<const float4*>(vp + i);
        Vt[sd + i + 0][srow] = f2bf(vf.x);
        Vt[sd + i + 1][srow] = f2bf(vf.y);
        Vt[sd + i + 2][srow] = f2bf(vf.z);
        Vt[sd + i + 3][srow] = f2bf(vf.w);
      }
    }
    __syncthreads();
    f32x4 sacc[4];
#pragma unroll
    for (int t = 0; t < 4; ++t) sacc[t] = (f32x4){0.f, 0.f, 0.f, 0.f};
#pragma unroll
    for (int t = 0; t < 4; ++t) {
#pragma unroll
      for (int c = 0; c < 2; ++c) {
        sv8 khv = *reinterpret_cast<const sv8*>(&Khi[t * 16 + lc][c * 32 + kg]);
        sv8 klv = *reinterpret_cast<const sv8*>(&Klo[t * 16 + lc][c * 32 + kg]);
        sacc[t] = mfma_bf16(qh[c], khv, sacc[t]);
        sacc[t] = mfma_bf16(qh[c], klv, sacc[t]);
        sacc[t] = mfma_bf16(ql[c], khv, sacc[t]);
      }
    }
    float p[4][4], pm[4], rs[4];
#pragma unroll
    for (int r = 0; r < 4; ++r) {
      float a = fmaxf(fmaxf(sacc[0][r], sacc[1][r]), fmaxf(sacc[2][r], sacc[3][r]));
      pm[r] = a * scale;
    }
#pragma unroll
    for (int msk = 1; msk < 16; msk <<= 1)
#pragma unroll
      for (int r = 0; r < 4; ++r) pm[r] = fmaxf(pm[r], __shfl_xor(pm[r], msk));
#pragma unroll
    for (int r = 0; r < 4; ++r) {
      float mnew = fmaxf(mrun[r], pm[r]);
      float fsc = __expf(mrun[r] - mnew);
      mrun[r] = mnew;
      float s0 = 0.f;
#pragma unroll
      for (int t = 0; t < 4; ++t) {
        float pv = __expf(sacc[t][r] * scale - mnew);
        p[t][r] = pv; s0 += pv;
      }
      rs[r] = s0;
      lrun[r] *= fsc;
#pragma unroll
      for (int t = 0; t < 4; ++t) oacc[t][r] *= fsc;
    }
#pragma unroll
    for (int msk = 1; msk < 16; msk <<= 1)
#pragma unroll
      for (int r = 0; r < 4; ++r) rs[r] += __shfl_xor(rs[r], msk);
#pragma unroll
    for (int r = 0; r < 4; ++r) lrun[r] += rs[r];
#pragma unroll
    for (int r = 0; r < 4; ++r)
#pragma unroll
      for (int t = 0; t < 4; ++t)
        Pl[wave][lg * 4 + r][t * 16 + lc] = f2bf(p[t][r]);
#pragma unroll
    for (int dt = 0; dt < 4; ++dt) {
#pragma unroll
      for (int kc = 0; kc < 2; ++kc) {
        sv8 pa = *reinterpret_cast<const sv8*>(&Pl[wave][lc][kc * 32 + kg]);
        sv8 vb = *reinterpret_cast<const sv8*>(&Vt[dt * 16 + lc][kc * 32 + kg]);
        oacc[dt] = mfma_bf16(pa, vb, oacc[dt]);
      }
    }
    __syncthreads();
  }
  float* op = Og + headoff + (size_t)(q0 + wave * 16) * D_DIM;
#pragma unroll
  for (int r = 0; r < 4; ++r) {
    float inv = 1.0f / lrun[r];
    int row = lg * 4 + r;
#pragma unroll
    for (int dt = 0; dt < 4; ++dt)
      op[(size_t)row * D_DIM + dt * 16 + lc] = oacc[dt][r] * inv;
  }
}

extern "C" void kernel_launch(void* const* d_in, const int* in_sizes, int n_in,
                              void* d_out, int out_size, void* d_ws, size_t ws_size,
                              hipStream_t stream) {
  const float* Q = (const float*)d_in[0];
  const float* K = (const float*)d_in[1];
  const float* V = (const float*)d_in[2];
  float* O = (float*)d_out;
  const size_t need = (size_t)NBH * NT * TILE_SHORTS * sizeof(short);  // 32 MB
  if (ws_size >= need) {
    prep_kv<<<dim3(NT, NBH), dim3(256), 0, stream>>>(K, V, (unsigned short*)d_ws);
    attn_fwd<<<dim3(NBH, S_LEN / QB), dim3(256), 0, stream>>>(Q, (const unsigned short*)d_ws, O);
  } else {
    attn_fwd_v1<<<dim3(S_LEN / QB, NBH), dim3(256), 0, stream>>>(Q, K, V, O);
  }
}

// Round 5
// 162.856 us; speedup vs baseline: 1.9875x; 1.0670x over previous
//
#include <hip/hip_runtime.h>
#include <hip/hip_bf16.h>
#include <stdint.h>

#define S_LEN 2048
#define D_DIM 64
#define NBH   64              // B*H
#define QB    128             // q rows per block (16 per wave, 8 waves)
#define NT    (S_LEN / 64)    // 32 kv tiles
#define TILE_SHORTS 8192      // 16KB per kv tile: K frags 8KB + V frags 8KB

typedef __bf16 bf8_t __attribute__((ext_vector_type(8)));
typedef short  sv8   __attribute__((ext_vector_type(8)));
typedef float  f32x4 __attribute__((ext_vector_type(4)));
typedef __attribute__((address_space(1))) uint32_t gu32;
typedef __attribute__((address_space(3))) uint32_t lu32;

static __device__ __forceinline__ unsigned short f2bf(float x) {
  union { float f; unsigned int u; } v; v.f = x;
  unsigned int r = v.u + 0x7FFFu + ((v.u >> 16) & 1u);  // RNE
  return (unsigned short)(r >> 16);
}
static __device__ __forceinline__ float bf2f(unsigned short h) {
  union { float f; unsigned int u; } v; v.u = ((unsigned int)h) << 16;
  return v.f;
}
static __device__ __forceinline__ uint32_t cvtpk(float a, float b) {
  union { __hip_bfloat162 h; uint32_t u; } r;
  r.h = __float22bfloat162_rn(make_float2(a, b));   // v_cvt_pk_bf16_f32
  return r.u;
}
static __device__ __forceinline__ f32x4 mfma_bf16(sv8 a, sv8 b, f32x4 c) {
  union { sv8 s; bf8_t b; } ua, ub; ua.s = a; ub.s = b;
  return __builtin_amdgcn_mfma_f32_16x16x32_bf16(ua.b, ub.b, c, 0, 0, 0);
}

// ---------------- pre-pass: K,V fp32 -> bf16 MFMA fragment order in d_ws ----
// K slots 0..511, V slots 512..1023 (granule = 16B per (chunk,lane)).
// V granules for lanes>=32 have their 8B halves swapped: the in-kernel
// bpermute P-exchange delivers those lanes' A-fragments with k-slots j^4;
// swapping V's halves applies the same permutation to B so it cancels.
extern "C" __global__ void __launch_bounds__(256)
prep_kv(const float* __restrict__ Kg, const float* __restrict__ Vg,
        unsigned short* __restrict__ Wf) {
  const int tile = blockIdx.x, bh = blockIdx.y, tid = threadIdx.x;
  const size_t in_head = (size_t)bh * S_LEN * D_DIM;
  unsigned short* out = Wf + (size_t)(bh * NT + tile) * TILE_SHORTS;

#pragma unroll
  for (int k8 = 0; k8 < 2; ++k8) {     // K slots
    int s = tid + 256 * k8;
    int chunk = s >> 6, lane = s & 63;
    int t = chunk >> 1, c = chunk & 1, lc = lane & 15, lg = lane >> 4;
    const float* p = Kg + in_head + (size_t)(tile * 64 + 16 * t + lc) * D_DIM + 32 * c + 8 * lg;
    float4 f0 = *(const float4*)p;
    float4 f1 = *(const float4*)(p + 4);
    uint4 w;
    w.x = cvtpk(f0.x, f0.y);
    w.y = cvtpk(f0.z, f0.w);
    w.z = cvtpk(f1.x, f1.y);
    w.w = cvtpk(f1.z, f1.w);
    *(uint4*)(out + (size_t)s * 8) = w;
  }
#pragma unroll
  for (int k8 = 0; k8 < 2; ++k8) {     // V slots (transpose)
    int s = tid + 256 * k8;
    int chunk = s >> 6, lane = s & 63;
    int dt = chunk >> 1, kc = chunk & 1, lc = lane & 15, lg = lane >> 4;
    const float* p = Vg + in_head + (size_t)(tile * 64 + 32 * kc + 8 * lg) * D_DIM + 16 * dt + lc;
    uint32_t h0 = cvtpk(p[0 * D_DIM], p[1 * D_DIM]);
    uint32_t h1 = cvtpk(p[2 * D_DIM], p[3 * D_DIM]);
    uint32_t h2 = cvtpk(p[4 * D_DIM], p[5 * D_DIM]);
    uint32_t h3 = cvtpk(p[6 * D_DIM], p[7 * D_DIM]);
    uint4 w;
    if (lane >= 32) { w.x = h2; w.y = h3; w.z = h0; w.w = h1; }
    else            { w.x = h0; w.y = h1; w.z = h2; w.w = h3; }
    *(uint4*)(out + (size_t)(512 + s) * 8) = w;
  }
}

// ---------------- main attention kernel (8 waves / 512 threads) -------------
extern "C" __global__ void __launch_bounds__(512)
attn_fwd(const float* __restrict__ Qg, const unsigned short* __restrict__ Wf,
         float* __restrict__ Og) {
  __shared__ short KV[2][TILE_SHORTS];  // double-buffered tile (32KB total)

  const int tid = threadIdx.x, wave = tid >> 6, lane = tid & 63;
  const int lg = lane >> 4, lc = lane & 15;
  const int bh = blockIdx.x, q0 = blockIdx.y * QB;   // bh on x: XCD = bh%8
  const size_t headoff = (size_t)bh * S_LEN * D_DIM;

  // Q B-fragments, pre-scaled by (1/sqrt(12))*log2(e), hi/lo split
  const float s2 = 0.28867513459481287f * 1.44269504088896340f;
  sv8 qh[2], ql[2];
  {
    const float* qp = Qg + headoff + (size_t)(q0 + wave * 16 + lc) * D_DIM;
#pragma unroll
    for (int c = 0; c < 2; ++c) {
      float4 a0 = *(const float4*)(qp + c * 32 + 8 * lg);
      float4 a1 = *(const float4*)(qp + c * 32 + 8 * lg + 4);
      float qv[8] = {a0.x, a0.y, a0.z, a0.w, a1.x, a1.y, a1.z, a1.w};
#pragma unroll
      for (int j = 0; j < 8; ++j) {
        float q = qv[j] * s2;
        unsigned short h = f2bf(q);
        qh[c][j] = (short)h;
        ql[c][j] = (short)f2bf(q - bf2f(h));
      }
    }
  }

  float mrun = -__builtin_inff(), lrun = 0.f;
  f32x4 oacc[4];
#pragma unroll
  for (int t = 0; t < 4; ++t) oacc[t] = (f32x4){0.f, 0.f, 0.f, 0.f};

  // bpermute exchange constants (hoisted):
  // round A srcs xor {0,48,48,0}, round B srcs xor {16,32,32,16} per lg
  const int addrA = (lane ^ (((lg == 1) || (lg == 2)) ? 48 : 0)) << 2;
  const int addrB = (lane ^ (((lg == 0) || (lg == 3)) ? 16 : 32)) << 2;
  const bool godd = (lg & 1);

  // running staging pointer (advances one 16KB tile per stage);
  // each of 8 waves stages 2KB (2 x 1KB gload_lds)
  const gu32* sptr = (const gu32*)((const uint32_t*)Wf + (size_t)bh * NT * 4096)
                   + wave * 512 + lane * 4;

  auto stage = [&](int buf) {
    lu32* dst = (lu32*)&KV[buf][wave * 1024];
#pragma unroll
    for (int s4 = 0; s4 < 2; ++s4)
      __builtin_amdgcn_global_load_lds(sptr + s4 * 256, dst + s4 * 256, 16, 0, 0);
    sptr += 4096;
  };

  auto compute = [&](const short* base) {
    f32x4 sacc[4];
#pragma unroll
    for (int t = 0; t < 4; ++t) sacc[t] = (f32x4){0.f, 0.f, 0.f, 0.f};
    __builtin_amdgcn_s_setprio(1);
#pragma unroll
    for (int t = 0; t < 4; ++t) {
#pragma unroll
      for (int c = 0; c < 2; ++c) {
        sv8 kf = *(const sv8*)(base + (t * 2 + c) * 512 + lane * 8);
        sacc[t] = mfma_bf16(kf, qh[c], sacc[t]);
        sacc[t] = mfma_bf16(kf, ql[c], sacc[t]);
      }
    }
    __builtin_amdgcn_s_setprio(0);

    // row max: left-assoc chains (v_max3-fusable), then 2 cross-lane hops
    float mt0 = fmaxf(fmaxf(fmaxf(sacc[0][0], sacc[0][1]), sacc[0][2]), sacc[0][3]);
    float mt1 = fmaxf(fmaxf(fmaxf(sacc[1][0], sacc[1][1]), sacc[1][2]), sacc[1][3]);
    float mt2 = fmaxf(fmaxf(fmaxf(sacc[2][0], sacc[2][1]), sacc[2][2]), sacc[2][3]);
    float mt3 = fmaxf(fmaxf(fmaxf(sacc[3][0], sacc[3][1]), sacc[3][2]), sacc[3][3]);
    float pm = fmaxf(fmaxf(fmaxf(mt0, mt1), mt2), mt3);
    pm = fmaxf(pm, __shfl_xor(pm, 16));
    pm = fmaxf(pm, __shfl_xor(pm, 32));

    // T13 defer-rescale
    const bool noresc = __all(pm - mrun <= 8.0f);
    float fsc = 1.0f;
    if (!noresc) {
      float mnew = fmaxf(mrun, pm);
      fsc = exp2f(mrun - mnew);
      mrun = mnew;
    }
    float p[4][4], rt[4];
#pragma unroll
    for (int t = 0; t < 4; ++t) {
#pragma unroll
      for (int r = 0; r < 4; ++r) p[t][r] = exp2f(sacc[t][r] - mrun);
      rt[t] = (p[t][0] + p[t][1]) + (p[t][2] + p[t][3]);
    }
    float rs = (rt[0] + rt[1]) + (rt[2] + rt[3]);
    rs += __shfl_xor(rs, 16);
    rs += __shfl_xor(rs, 32);
    if (!noresc) {
      lrun = lrun * fsc + rs;
      float fq[4];
#pragma unroll
      for (int r = 0; r < 4; ++r) fq[r] = __shfl(fsc, 4 * lg + r);
#pragma unroll
      for (int dt = 0; dt < 4; ++dt)
#pragma unroll
        for (int r = 0; r < 4; ++r) oacc[dt][r] *= fq[r];
    } else {
      lrun += rs;
    }

    // pack P to bf16 pairs: w[t][0]=(kv 16t+4lg, +1), w[t][1]=(kv 16t+4lg+2, +3)
    uint32_t w[4][2];
#pragma unroll
    for (int t = 0; t < 4; ++t) {
      w[t][0] = cvtpk(p[t][0], p[t][1]);
      w[t][1] = cvtpk(p[t][2], p[t][3]);
    }

    // in-register P redistribution: 2 bijective bpermute rounds per kc.
    // round A: src contributes w[2kc + (g&1)]; round B: w[2kc + !(g&1)].
    // lanes>=32 receive k-slots j^4 — cancelled by prep_kv's V half-swap.
    sv8 pa[2];
#pragma unroll
    for (int kc = 0; kc < 2; ++kc) {
      uint32_t aLo = godd ? w[2 * kc + 1][0] : w[2 * kc][0];
      uint32_t aHi = godd ? w[2 * kc + 1][1] : w[2 * kc][1];
      uint32_t bLo = godd ? w[2 * kc][0]     : w[2 * kc + 1][0];
      uint32_t bHi = godd ? w[2 * kc][1]     : w[2 * kc + 1][1];
      union { int i[4]; sv8 s; } pu;
      pu.i[0] = __builtin_amdgcn_ds_bpermute(addrA, (int)aLo);
      pu.i[1] = __builtin_amdgcn_ds_bpermute(addrA, (int)aHi);
      pu.i[2] = __builtin_amdgcn_ds_bpermute(addrB, (int)bLo);
      pu.i[3] = __builtin_amdgcn_ds_bpermute(addrB, (int)bHi);
      pa[kc] = pu.s;
    }

    __builtin_amdgcn_s_setprio(1);
#pragma unroll
    for (int dt = 0; dt < 4; ++dt) {
      sv8 vb0 = *(const sv8*)(base + 4096 + (dt * 2 + 0) * 512 + lane * 8);
      sv8 vb1 = *(const sv8*)(base + 4096 + (dt * 2 + 1) * 512 + lane * 8);
      oacc[dt] = mfma_bf16(pa[0], vb0, oacc[dt]);
      oacc[dt] = mfma_bf16(pa[1], vb1, oacc[dt]);
    }
    __builtin_amdgcn_s_setprio(0);
  };

  // double-buffered pipeline, 2 tiles/iter, compile-time buffer indices
  stage(0);
  for (int it = 0; it < NT / 2 - 1; ++it) {
    stage(1);
    asm volatile("s_waitcnt vmcnt(2)" ::: "memory");
    __builtin_amdgcn_s_barrier();
    asm volatile("" ::: "memory");
    compute(&KV[0][0]);
    asm volatile("s_waitcnt lgkmcnt(0)" ::: "memory");
    __builtin_amdgcn_s_barrier();
    asm volatile("" ::: "memory");
    stage(0);
    asm volatile("s_waitcnt vmcnt(2)" ::: "memory");
    __builtin_amdgcn_s_barrier();
    asm volatile("" ::: "memory");
    compute(&KV[1][0]);
    asm volatile("s_waitcnt lgkmcnt(0)" ::: "memory");
    __builtin_amdgcn_s_barrier();
    asm volatile("" ::: "memory");
  }
  stage(1);                                        // tile NT-1
  asm volatile("s_waitcnt vmcnt(2)" ::: "memory"); // tile NT-2 ready
  __builtin_amdgcn_s_barrier();
  asm volatile("" ::: "memory");
  compute(&KV[0][0]);
  asm volatile("s_waitcnt vmcnt(0)" ::: "memory"); // tile NT-1 ready
  __builtin_amdgcn_s_barrier();
  asm volatile("" ::: "memory");
  compute(&KV[1][0]);

  // epilogue: normalize + store
  float linv[4];
#pragma unroll
  for (int r = 0; r < 4; ++r) {
    float l = __shfl(lrun, 4 * lg + r);
    linv[r] = 1.0f / l;
  }
  float* op = Og + headoff + (size_t)(q0 + wave * 16) * D_DIM;
#pragma unroll
  for (int dt = 0; dt < 4; ++dt)
#pragma unroll
    for (int r = 0; r < 4; ++r)
      op[(size_t)(4 * lg + r) * D_DIM + 16 * dt + lc] = oacc[dt][r] * linv[r];
}

// ---------------- fallback (round-1 kernel, used only if ws too small) ------
#define DPAD 72
extern "C" __global__ void __launch_bounds__(256)
attn_fwd_v1(const float* __restrict__ Qg, const float* __restrict__ Kg,
            const float* __restrict__ Vg, float* __restrict__ Og) {
  __shared__ unsigned short Khi[64][DPAD];
  __shared__ unsigned short Klo[64][DPAD];
  __shared__ unsigned short Vt[D_DIM][DPAD];
  __shared__ unsigned short Pl[4][16][DPAD];

  const int tid = threadIdx.x, wave = tid >> 6, lane = tid & 63;
  const int bh = blockIdx.y, q0 = blockIdx.x * 64;
  const int lg = lane >> 4, lc = lane & 15, kg = lg << 3;
  const size_t headoff = (size_t)bh * S_LEN * D_DIM;
  const float scale = 0.28867513459481287f;

  sv8 qh[2], ql[2];
  {
    const float* qp = Qg + headoff + (size_t)(q0 + wave * 16 + lc) * D_DIM;
#pragma unroll
    for (int c = 0; c < 2; ++c) {
      const float4 a0 = *reinterpret_cast<const float4*>(qp + c * 32 + kg);
      const float4 a1 = *reinterpret_cast<const float4*>(qp + c * 32 + kg + 4);
      float qv[8] = {a0.x, a0.y, a0.z, a0.w, a1.x, a1.y, a1.z, a1.w};
#pragma unroll
      for (int j = 0; j < 8; ++j) {
        unsigned short h = f2bf(qv[j]);
        qh[c][j] = (short)h;
        ql[c][j] = (short)f2bf(qv[j] - bf2f(h));
      }
    }
  }
  float mrun[4], lrun[4];
  f32x4 oacc[4];
#pragma unroll
  for (int r = 0; r < 4; ++r) { mrun[r] = -__builtin_inff(); lrun[r] = 0.f; }
#pragma unroll
  for (int t = 0; t < 4; ++t) oacc[t] = (f32x4){0.f, 0.f, 0.f, 0.f};

  const int srow = tid >> 2, sd = (tid & 3) << 4;
  const float* kbase = Kg + headoff + sd;
  const float* vbase = Vg + headoff + sd;

  for (int kv0 = 0; kv0 < S_LEN; kv0 += 64) {
    {
      const float* kp = kbase + (size_t)(kv0 + srow) * D_DIM;
      const float* vp = vbase + (size_t)(kv0 + srow) * D_DIM;
#pragma unroll
      for (int i = 0; i < 16; i += 4) {
        float4 kf = *reinterpret_cast<const float4*>(kp + i);
        unsigned short h0 = f2bf(kf.x), h1 = f2bf(kf.y), h2 = f2bf(kf.z), h3 = f2bf(kf.w);
        *reinterpret_cast<uint64_t*>(&Khi[srow][sd + i]) =
            (uint64_t)h0 | ((uint64_t)h1 << 16) | ((uint64_t)h2 << 32) | ((uint64_t)h3 << 48);
        unsigned short l0 = f2bf(kf.x - bf2f(h0)), l1 = f2bf(kf.y - bf2f(h1));
        unsigned short l2 = f2bf(kf.z - bf2f(h2)), l3 = f2bf(kf.w - bf2f(h3));
        *reinterpret_cast<uint64_t*>(&Klo[srow][sd + i]) =
            (uint64_t)l0 | ((uint64_t)l1 << 16) | ((uint64_t)l2 << 32) | ((uint64_t)l3 << 48);
        float4 vf = *reinterpret_cast<const float4*>(vp + i);
        Vt[sd + i + 0][srow] = f2bf(vf.x);
        Vt[sd + i + 1][srow] = f2bf(vf.y);
        Vt[sd + i + 2][srow] = f2bf(vf.z);
        Vt[sd + i + 3][srow] = f2bf(vf.w);
      }
    }
    __syncthreads();
    f32x4 sacc[4];
#pragma unroll
    for (int t = 0; t < 4; ++t) sacc[t] = (f32x4){0.f, 0.f, 0.f, 0.f};
#pragma unroll
    for (int t = 0; t < 4; ++t) {
#pragma unroll
      for (int c = 0; c < 2; ++c) {
        sv8 khv = *reinterpret_cast<const sv8*>(&Khi[t * 16 + lc][c * 32 + kg]);
        sv8 klv = *reinterpret_cast<const sv8*>(&Klo[t * 16 + lc][c * 32 + kg]);
        sacc[t] = mfma_bf16(qh[c], khv, sacc[t]);
        sacc[t] = mfma_bf16(qh[c], klv, sacc[t]);
        sacc[t] = mfma_bf16(ql[c], khv, sacc[t]);
      }
    }
    float p[4][4], pm[4], rs[4];
#pragma unroll
    for (int r = 0; r < 4; ++r) {
      float a = fmaxf(fmaxf(sacc[0][r], sacc[1][r]), fmaxf(sacc[2][r], sacc[3][r]));
      pm[r] = a * scale;
    }
#pragma unroll
    for (int msk = 1; msk < 16; msk <<= 1)
#pragma unroll
      for (int r = 0; r < 4; ++r) pm[r] = fmaxf(pm[r], __shfl_xor(pm[r], msk));
#pragma unroll
    for (int r = 0; r < 4; ++r) {
      float mnew = fmaxf(mrun[r], pm[r]);
      float fsc = __expf(mrun[r] - mnew);
      mrun[r] = mnew;
      float s0 = 0.f;
#pragma unroll
      for (int t = 0; t < 4; ++t) {
        float pv = __expf(sacc[t][r] * scale - mnew);
        p[t][r] = pv; s0 += pv;
      }
      rs[r] = s0;
      lrun[r] *= fsc;
#pragma unroll
      for (int t = 0; t < 4; ++t) oacc[t][r] *= fsc;
    }
#pragma unroll
    for (int msk = 1; msk < 16; msk <<= 1)
#pragma unroll
      for (int r = 0; r < 4; ++r) rs[r] += __shfl_xor(rs[r], msk);
#pragma unroll
    for (int r = 0; r < 4; ++r) lrun[r] += rs[r];
#pragma unroll
    for (int r = 0; r < 4; ++r)
#pragma unroll
      for (int t = 0; t < 4; ++t)
        Pl[wave][lg * 4 + r][t * 16 + lc] = f2bf(p[t][r]);
#pragma unroll
    for (int dt = 0; dt < 4; ++dt) {
#pragma unroll
      for (int kc = 0; kc < 2; ++kc) {
        sv8 pa = *reinterpret_cast<const sv8*>(&Pl[wave][lc][kc * 32 + kg]);
        sv8 vb = *reinterpret_cast<const sv8*>(&Vt[dt * 16 + lc][kc * 32 + kg]);
        oacc[dt] = mfma_bf16(pa, vb, oacc[dt]);
      }
    }
    __syncthreads();
  }
  float* op = Og + headoff + (size_t)(q0 + wave * 16) * D_DIM;
#pragma unroll
  for (int r = 0; r < 4; ++r) {
    float inv = 1.0f / lrun[r];
    int row = lg * 4 + r;
#pragma unroll
    for (int dt = 0; dt < 4; ++dt)
      op[(size_t)row * D_DIM + dt * 16 + lc] = oacc[dt][r] * inv;
  }
}

extern "C" void kernel_launch(void* const* d_in, const int* in_sizes, int n_in,
                              void* d_out, int out_size, void* d_ws, size_t ws_size,
                              hipStream_t stream) {
  const float* Q = (const float*)d_in[0];
  const float* K = (const float*)d_in[1];
  const float* V = (const float*)d_in[2];
  float* O = (float*)d_out;
  const size_t need = (size_t)NBH * NT * TILE_SHORTS * sizeof(short);  // 32 MB
  if (ws_size >= need) {
    prep_kv<<<dim3(NT, NBH), dim3(256), 0, stream>>>(K, V, (unsigned short*)d_ws);
    attn_fwd<<<dim3(NBH, S_LEN / QB), dim3(512), 0, stream>>>(Q, (const unsigned short*)d_ws, O);
  } else {
    attn_fwd_v1<<<dim3(S_LEN / 64, NBH), dim3(256), 0, stream>>>(Q, K, V, O);
  }
}

// Round 6
// 155.539 us; speedup vs baseline: 2.0809x; 1.0470x over previous
//
#include <hip/hip_runtime.h>
#include <hip/hip_bf16.h>
#include <stdint.h>

#define S_LEN 2048
#define D_DIM 64
#define NBH   64              // B*H
#define QB    128             // q rows per block (32 per wave, 4 waves)
#define NT    (S_LEN / 64)    // 32 kv tiles
#define TILE_SHORTS 8192      // 16KB per kv tile: K frags 8KB + V frags 8KB

typedef __bf16 bf8_t  __attribute__((ext_vector_type(8)));
typedef short  sv8    __attribute__((ext_vector_type(8)));
typedef float  f32x16 __attribute__((ext_vector_type(16)));
typedef float  f32x4  __attribute__((ext_vector_type(4)));
typedef unsigned int u32x2 __attribute__((ext_vector_type(2)));
typedef __attribute__((address_space(1))) uint32_t gu32;
typedef __attribute__((address_space(3))) uint32_t lu32;

static __device__ __forceinline__ unsigned short f2bf(float x) {
  union { float f; unsigned int u; } v; v.f = x;
  unsigned int r = v.u + 0x7FFFu + ((v.u >> 16) & 1u);  // RNE
  return (unsigned short)(r >> 16);
}
static __device__ __forceinline__ float bf2f(unsigned short h) {
  union { float f; unsigned int u; } v; v.u = ((unsigned int)h) << 16;
  return v.f;
}
static __device__ __forceinline__ uint32_t cvtpk(float a, float b) {
  union { __hip_bfloat162 h; uint32_t u; } r;
  r.h = __float22bfloat162_rn(make_float2(a, b));
  return r.u;
}
static __device__ __forceinline__ f32x16 mfma32(sv8 a, sv8 b, f32x16 c) {
  union { sv8 s; bf8_t b; } ua, ub; ua.s = a; ub.s = b;
  return __builtin_amdgcn_mfma_f32_32x32x16_bf16(ua.b, ub.b, c, 0, 0, 0);
}

// ---------------- pre-pass: K,V fp32 -> bf16 32x32-MFMA A-frag granules -----
// per (bh,tile): 1024 slots x 16B.
//  K slots g*64+lane, g = h*4+c (h=kv-half, c=kstep):
//    elem j: K[kv0 + 32h + (lane&31)][16c + 8*(lane>>5) + j]
//  V slots 512 + g*64+lane, g = dh*4+ks  (V^T granules):
//    elem j: V[kv0 + 16ks + 8*(lane>>5) + j][32dh + (lane&31)]
extern "C" __global__ void __launch_bounds__(256)
prep_kv(const float* __restrict__ Kg, const float* __restrict__ Vg,
        unsigned short* __restrict__ Wf) {
  const int tile = blockIdx.x, bh = blockIdx.y, tid = threadIdx.x;
  const size_t in_head = (size_t)bh * S_LEN * D_DIM;
  unsigned short* out = Wf + (size_t)(bh * NT + tile) * TILE_SHORTS;

#pragma unroll
  for (int k8 = 0; k8 < 2; ++k8) {     // K granules
    int s = tid + 256 * k8;
    int g = s >> 6, lane = s & 63;
    int h = g >> 2, c = g & 3, l31 = lane & 31, hi = lane >> 5;
    const float* p = Kg + in_head + (size_t)(tile * 64 + 32 * h + l31) * D_DIM + 16 * c + 8 * hi;
    float4 f0 = *(const float4*)p;
    float4 f1 = *(const float4*)(p + 4);
    uint4 w;
    w.x = cvtpk(f0.x, f0.y);
    w.y = cvtpk(f0.z, f0.w);
    w.z = cvtpk(f1.x, f1.y);
    w.w = cvtpk(f1.z, f1.w);
    *(uint4*)(out + (size_t)s * 8) = w;
  }
#pragma unroll
  for (int k8 = 0; k8 < 2; ++k8) {     // V granules (transpose)
    int s = tid + 256 * k8;
    int g = s >> 6, lane = s & 63;
    int dh = g >> 2, ks = g & 3, l31 = lane & 31, hi = lane >> 5;
    const float* p = Vg + in_head + (size_t)(tile * 64 + 16 * ks + 8 * hi) * D_DIM + 32 * dh + l31;
    uint4 w;
    w.x = cvtpk(p[0 * D_DIM], p[1 * D_DIM]);
    w.y = cvtpk(p[2 * D_DIM], p[3 * D_DIM]);
    w.z = cvtpk(p[4 * D_DIM], p[5 * D_DIM]);
    w.w = cvtpk(p[6 * D_DIM], p[7 * D_DIM]);
    *(uint4*)(out + (size_t)(512 + s) * 8) = w;
  }
}

// ---------------- main attention kernel: 4 waves x 32 q-rows, 32x32 MFMA ----
extern "C" __global__ void __launch_bounds__(256, 3)
attn_fwd(const float* __restrict__ Qg, const unsigned short* __restrict__ Wf,
         float* __restrict__ Og) {
  __shared__ short KV[2][TILE_SHORTS];  // double-buffered tile (32KB)

  const int tid = threadIdx.x, wave = tid >> 6, lane = tid & 63;
  const int l31 = lane & 31, hi = lane >> 5;
  const int bh = blockIdx.x, q0 = blockIdx.y * QB;   // bh on x: XCD = bh%8
  const size_t headoff = (size_t)bh * S_LEN * D_DIM;

  // Q B-fragments (16d x 32q): q = l31, d = 16c + 8hi + j. hi/lo split,
  // pre-scaled by (1/sqrt(12))*log2(e)
  const float s2 = 0.28867513459481287f * 1.44269504088896340f;
  sv8 qh[4], ql[4];
  {
    const float* qp = Qg + headoff + (size_t)(q0 + wave * 32 + l31) * D_DIM;
#pragma unroll
    for (int c = 0; c < 4; ++c) {
      float4 a0 = *(const float4*)(qp + 16 * c + 8 * hi);
      float4 a1 = *(const float4*)(qp + 16 * c + 8 * hi + 4);
      float qv[8] = {a0.x, a0.y, a0.z, a0.w, a1.x, a1.y, a1.z, a1.w};
#pragma unroll
      for (int j = 0; j < 8; ++j) {
        float q = qv[j] * s2;
        unsigned short h = f2bf(q);
        qh[c][j] = (short)h;
        ql[c][j] = (short)f2bf(q - bf2f(h));
      }
    }
  }

  float mrun = -__builtin_inff(), lrun = 0.f;
  f32x16 oacc[2];
  const f32x16 z16 = {0.f,0.f,0.f,0.f,0.f,0.f,0.f,0.f,0.f,0.f,0.f,0.f,0.f,0.f,0.f,0.f};
  oacc[0] = z16; oacc[1] = z16;

  // running staging pointer; each of 4 waves stages 4KB (4 x 1KB gload_lds)
  const gu32* sptr = (const gu32*)((const uint32_t*)Wf + (size_t)bh * NT * 4096)
                   + wave * 1024 + lane * 4;

  auto stage = [&](int buf) {
    lu32* dst = (lu32*)&KV[buf][wave * 2048];
#pragma unroll
    for (int s4 = 0; s4 < 4; ++s4)
      __builtin_amdgcn_global_load_lds(sptr + s4 * 256, dst + s4 * 256, 16, 0, 0);
    sptr += 4096;
  };

  auto compute = [&](const short* base) {
    // S^T = K . Q^T : D rows = kv, cols = q (= l31 for BOTH lane halves)
    f32x16 sacc[2];
    sacc[0] = z16; sacc[1] = z16;
    __builtin_amdgcn_s_setprio(1);
#pragma unroll
    for (int h = 0; h < 2; ++h) {
#pragma unroll
      for (int c = 0; c < 4; ++c) {
        sv8 kf = *(const sv8*)(base + ((h * 4 + c) * 64 + lane) * 8);
        sacc[h] = mfma32(kf, qh[c], sacc[h]);
        sacc[h] = mfma32(kf, ql[c], sacc[h]);
      }
    }
    __builtin_amdgcn_s_setprio(0);

    // row max over this lane's 32 kv slots, + 1 hop (lane <-> lane^32)
    float m0 = sacc[0][0], m1 = sacc[0][1], m2 = sacc[0][2], m3 = sacc[0][3];
#pragma unroll
    for (int r = 4; r < 16; r += 4) {
      m0 = fmaxf(m0, sacc[0][r + 0]); m1 = fmaxf(m1, sacc[0][r + 1]);
      m2 = fmaxf(m2, sacc[0][r + 2]); m3 = fmaxf(m3, sacc[0][r + 3]);
    }
#pragma unroll
    for (int r = 0; r < 16; r += 4) {
      m0 = fmaxf(m0, sacc[1][r + 0]); m1 = fmaxf(m1, sacc[1][r + 1]);
      m2 = fmaxf(m2, sacc[1][r + 2]); m3 = fmaxf(m3, sacc[1][r + 3]);
    }
    float pm = fmaxf(fmaxf(m0, m1), fmaxf(m2, m3));
    pm = fmaxf(pm, __shfl_xor(pm, 32));

    // T13 defer-rescale
    const bool noresc = __all(pm - mrun <= 8.0f);
    float fsc = 1.0f;
    if (!noresc) {
      float mnew = fmaxf(mrun, pm);
      fsc = exp2f(mrun - mnew);
      mrun = mnew;
    }

    // exp + pack + permlane exchange -> P^T B-fragments pa[ks][word]
    uint32_t pa[4][4];
    float rs = 0.f;
#pragma unroll
    for (int h = 0; h < 2; ++h) {
      float p[16];
#pragma unroll
      for (int r = 0; r < 16; ++r) p[r] = exp2f(sacc[h][r] - mrun);
#pragma unroll
      for (int r = 0; r < 16; ++r) rs += p[r];
      uint32_t A0 = cvtpk(p[0], p[1]),  A1 = cvtpk(p[2], p[3]);
      uint32_t B0 = cvtpk(p[4], p[5]),  B1 = cvtpk(p[6], p[7]);
      uint32_t C0 = cvtpk(p[8], p[9]),  C1 = cvtpk(p[10], p[11]);
      uint32_t D0 = cvtpk(p[12], p[13]), D1 = cvtpk(p[14], p[15]);
      u32x2 r0 = __builtin_amdgcn_permlane32_swap(A0, B0, false, false);
      u32x2 r1 = __builtin_amdgcn_permlane32_swap(A1, B1, false, false);
      u32x2 r2 = __builtin_amdgcn_permlane32_swap(C0, D0, false, false);
      u32x2 r3 = __builtin_amdgcn_permlane32_swap(C1, D1, false, false);
      pa[2 * h][0] = r0[0]; pa[2 * h][2] = r0[1];
      pa[2 * h][1] = r1[0]; pa[2 * h][3] = r1[1];
      pa[2 * h + 1][0] = r2[0]; pa[2 * h + 1][2] = r2[1];
      pa[2 * h + 1][1] = r3[0]; pa[2 * h + 1][3] = r3[1];
    }
    rs += __shfl_xor(rs, 32);
    if (!noresc) {
      lrun = lrun * fsc + rs;
#pragma unroll
      for (int dh = 0; dh < 2; ++dh)
#pragma unroll
        for (int i = 0; i < 16; ++i) oacc[dh][i] *= fsc;
    } else {
      lrun += rs;
    }

    // O^T += V^T . P^T  (D rows = d, cols = q = l31)
    __builtin_amdgcn_s_setprio(1);
#pragma unroll
    for (int dh = 0; dh < 2; ++dh) {
#pragma unroll
      for (int ks = 0; ks < 4; ++ks) {
        sv8 vb = *(const sv8*)(base + 4096 + ((dh * 4 + ks) * 64 + lane) * 8);
        union { uint32_t u[4]; sv8 s; } pf;
        pf.u[0] = pa[ks][0]; pf.u[1] = pa[ks][1];
        pf.u[2] = pa[ks][2]; pf.u[3] = pa[ks][3];
        oacc[dh] = mfma32(vb, pf.s, oacc[dh]);
      }
    }
    __builtin_amdgcn_s_setprio(0);
  };

  // double-buffered pipeline, 2 tiles/iter, compile-time buffer indices
  stage(0);
  for (int it = 0; it < NT / 2 - 1; ++it) {
    stage(1);
    asm volatile("s_waitcnt vmcnt(4)" ::: "memory");
    __builtin_amdgcn_s_barrier();
    asm volatile("" ::: "memory");
    compute(&KV[0][0]);
    asm volatile("s_waitcnt lgkmcnt(0)" ::: "memory");
    __builtin_amdgcn_s_barrier();
    asm volatile("" ::: "memory");
    stage(0);
    asm volatile("s_waitcnt vmcnt(4)" ::: "memory");
    __builtin_amdgcn_s_barrier();
    asm volatile("" ::: "memory");
    compute(&KV[1][0]);
    asm volatile("s_waitcnt lgkmcnt(0)" ::: "memory");
    __builtin_amdgcn_s_barrier();
    asm volatile("" ::: "memory");
  }
  stage(1);
  asm volatile("s_waitcnt vmcnt(4)" ::: "memory");
  __builtin_amdgcn_s_barrier();
  asm volatile("" ::: "memory");
  compute(&KV[0][0]);
  asm volatile("s_waitcnt vmcnt(0)" ::: "memory");
  __builtin_amdgcn_s_barrier();
  asm volatile("" ::: "memory");
  compute(&KV[1][0]);

  // epilogue: normalize + store (no cross-lane broadcast needed: q = l31)
  const float linv = 1.0f / lrun;
  float* op = Og + headoff + (size_t)(q0 + wave * 32 + l31) * D_DIM;
#pragma unroll
  for (int dh = 0; dh < 2; ++dh) {
#pragma unroll
    for (int g = 0; g < 4; ++g) {
      float4 v;
      v.x = oacc[dh][4 * g + 0] * linv;
      v.y = oacc[dh][4 * g + 1] * linv;
      v.z = oacc[dh][4 * g + 2] * linv;
      v.w = oacc[dh][4 * g + 3] * linv;
      *(float4*)(op + 32 * dh + 8 * g + 4 * hi) = v;
    }
  }
}

// ---------------- fallback (round-1 kernel, used only if ws too small) ------
#define DPAD 72
typedef float f32x4b __attribute__((ext_vector_type(4)));
static __device__ __forceinline__ f32x4 mfma16(sv8 a, sv8 b, f32x4 c) {
  union { sv8 s; bf8_t b; } ua, ub; ua.s = a; ub.s = b;
  return __builtin_amdgcn_mfma_f32_16x16x32_bf16(ua.b, ub.b, c, 0, 0, 0);
}
extern "C" __global__ void __launch_bounds__(256)
attn_fwd_v1(const float* __restrict__ Qg, const float* __restrict__ Kg,
            const float* __restrict__ Vg, float* __restrict__ Og) {
  __shared__ unsigned short Khi[64][DPAD];
  __shared__ unsigned short Klo[64][DPAD];
  __shared__ unsigned short Vt[D_DIM][DPAD];
  __shared__ unsigned short Pl[4][16][DPAD];

  const int tid = threadIdx.x, wave = tid >> 6, lane = tid & 63;
  const int bh = blockIdx.y, q0 = blockIdx.x * 64;
  const int lg = lane >> 4, lc = lane & 15, kg = lg << 3;
  const size_t headoff = (size_t)bh * S_LEN * D_DIM;
  const float scale = 0.28867513459481287f;

  sv8 qh[2], ql[2];
  {
    const float* qp = Qg + headoff + (size_t)(q0 + wave * 16 + lc) * D_DIM;
#pragma unroll
    for (int c = 0; c < 2; ++c) {
      const float4 a0 = *reinterpret_cast<const float4*>(qp + c * 32 + kg);
      const float4 a1 = *reinterpret_cast<const float4*>(qp + c * 32 + kg + 4);
      float qv[8] = {a0.x, a0.y, a0.z, a0.w, a1.x, a1.y, a1.z, a1.w};
#pragma unroll
      for (int j = 0; j < 8; ++j) {
        unsigned short h = f2bf(qv[j]);
        qh[c][j] = (short)h;
        ql[c][j] = (short)f2bf(qv[j] - bf2f(h));
      }
    }
  }
  float mrun[4], lrun[4];
  f32x4 oacc[4];
#pragma unroll
  for (int r = 0; r < 4; ++r) { mrun[r] = -__builtin_inff(); lrun[r] = 0.f; }
#pragma unroll
  for (int t = 0; t < 4; ++t) oacc[t] = (f32x4){0.f, 0.f, 0.f, 0.f};

  const int srow = tid >> 2, sd = (tid & 3) << 4;
  const float* kbase = Kg + headoff + sd;
  const float* vbase = Vg + headoff + sd;

  for (int kv0 = 0; kv0 < S_LEN; kv0 += 64) {
    {
      const float* kp = kbase + (size_t)(kv0 + srow) * D_DIM;
      const float* vp = vbase + (size_t)(kv0 + srow) * D_DIM;
#pragma unroll
      for (int i = 0; i < 16; i += 4) {
        float4 kf = *reinterpret_cast<const float4*>(kp + i);
        unsigned short h0 = f2bf(kf.x), h1 = f2bf(kf.y), h2 = f2bf(kf.z), h3 = f2bf(kf.w);
        *reinterpret_cast<uint64_t*>(&Khi[srow][sd + i]) =
            (uint64_t)h0 | ((uint64_t)h1 << 16) | ((uint64_t)h2 << 32) | ((uint64_t)h3 << 48);
        unsigned short l0 = f2bf(kf.x - bf2f(h0)), l1 = f2bf(kf.y - bf2f(h1));
        unsigned short l2 = f2bf(kf.z - bf2f(h2)), l3 = f2bf(kf.w - bf2f(h3));
        *reinterpret_cast<uint64_t*>(&Klo[srow][sd + i]) =
            (uint64_t)l0 | ((uint64_t)l1 << 16) | ((uint64_t)l2 << 32) | ((uint64_t)l3 << 48);
        float4 vf = *reinterpret_cast<const float4*>(vp + i);
        Vt[sd + i + 0][srow] = f2bf(vf.x);
        Vt[sd + i + 1][srow] = f2bf(vf.y);
        Vt[sd + i + 2][srow] = f2bf(vf.z);
        Vt[sd + i + 3][srow] = f2bf(vf.w);
      }
    }
    __syncthreads();
    f32x4 sacc[4];
#pragma unroll
    for (int t = 0; t < 4; ++t) sacc[t] = (f32x4){0.f, 0.f, 0.f, 0.f};
#pragma unroll
    for (int t = 0; t < 4; ++t) {
#pragma unroll
      for (int c = 0; c < 2; ++c) {
        sv8 khv = *reinterpret_cast<const sv8*>(&Khi[t * 16 + lc][c * 32 + kg]);
        sv8 klv = *reinterpret_cast<const sv8*>(&Klo[t * 16 + lc][c * 32 + kg]);
        sacc[t] = mfma16(qh[c], khv, sacc[t]);
        sacc[t] = mfma16(qh[c], klv, sacc[t]);
        sacc[t] = mfma16(ql[c], khv, sacc[t]);
      }
    }
    float p[4][4], pm[4], rs[4];
#pragma unroll
    for (int r = 0; r < 4; ++r) {
      float a = fmaxf(fmaxf(sacc[0][r], sacc[1][r]), fmaxf(sacc[2][r], sacc[3][r]));
      pm[r] = a * scale;
    }
#pragma unroll
    for (int msk = 1; msk < 16; msk <<= 1)
#pragma unroll
      for (int r = 0; r < 4; ++r) pm[r] = fmaxf(pm[r], __shfl_xor(pm[r], msk));
#pragma unroll
    for (int r = 0; r < 4; ++r) {
      float mnew = fmaxf(mrun[r], pm[r]);
      float fsc = __expf(mrun[r] - mnew);
      mrun[r] = mnew;
      float s0 = 0.f;
#pragma unroll
      for (int t = 0; t < 4; ++t) {
        float pv = __expf(sacc[t][r] * scale - mnew);
        p[t][r] = pv; s0 += pv;
      }
      rs[r] = s0;
      lrun[r] *= fsc;
#pragma unroll
      for (int t = 0; t < 4; ++t) oacc[t][r] *= fsc;
    }
#pragma unroll
    for (int msk = 1; msk < 16; msk <<= 1)
#pragma unroll
      for (int r = 0; r < 4; ++r) rs[r] += __shfl_xor(rs[r], msk);
#pragma unroll
    for (int r = 0; r < 4; ++r) lrun[r] += rs[r];
#pragma unroll
    for (int r = 0; r < 4; ++r)
#pragma unroll
      for (int t = 0; t < 4; ++t)
        Pl[wave][lg * 4 + r][t * 16 + lc] = f2bf(p[t][r]);
#pragma unroll
    for (int dt = 0; dt < 4; ++dt) {
#pragma unroll
      for (int kc = 0; kc < 2; ++kc) {
        sv8 pa = *reinterpret_cast<const sv8*>(&Pl[wave][lc][kc * 32 + kg]);
        sv8 vb = *reinterpret_cast<const sv8*>(&Vt[dt * 16 + lc][kc * 32 + kg]);
        oacc[dt] = mfma16(pa, vb, oacc[dt]);
      }
    }
    __syncthreads();
  }
  float* op = Og + headoff + (size_t)(q0 + wave * 16) * D_DIM;
#pragma unroll
  for (int r = 0; r < 4; ++r) {
    float inv = 1.0f / lrun[r];
    int row = lg * 4 + r;
#pragma unroll
    for (int dt = 0; dt < 4; ++dt)
      op[(size_t)row * D_DIM + dt * 16 + lc] = oacc[dt][r] * inv;
  }
}

extern "C" void kernel_launch(void* const* d_in, const int* in_sizes, int n_in,
                              void* d_out, int out_size, void* d_ws, size_t ws_size,
                              hipStream_t stream) {
  const float* Q = (const float*)d_in[0];
  const float* K = (const float*)d_in[1];
  const float* V = (const float*)d_in[2];
  float* O = (float*)d_out;
  const size_t need = (size_t)NBH * NT * TILE_SHORTS * sizeof(short);  // 32 MB
  if (ws_size >= need) {
    prep_kv<<<dim3(NT, NBH), dim3(256), 0, stream>>>(K, V, (unsigned short*)d_ws);
    attn_fwd<<<dim3(NBH, S_LEN / QB), dim3(256), 0, stream>>>(Q, (const unsigned short*)d_ws, O);
  } else {
    attn_fwd_v1<<<dim3(S_LEN / 64, NBH), dim3(256), 0, stream>>>(Q, K, V, O);
  }
}